// Round 12
// baseline (398.691 us; speedup 1.0000x reference)
//
#include <hip/hip_runtime.h>
#include <cmath>

// ---------------------------------------------------------------------------
// Problem constants: B=16, N=196, D=512, M=20, H=8, hd=64, k=51
//   tokens = 3136, 3D = 1536
// Algebra: h1 = Omg@(W1*Wo)^T + F@W1^T + (W1*bo + b1)  [Fenh eliminated]
// All GEMMs are pre-split bf16x3 MFMA (no on-the-fly splitting anywhere):
//   qkvw epilogue emits Q,K limbs + V limbs transposed; softmax emits P limbs.
// ---------------------------------------------------------------------------

typedef __attribute__((ext_vector_type(8))) short bf16x8v;
typedef __attribute__((ext_vector_type(4))) float f32x4v;

__device__ __forceinline__ unsigned short f2bf_rne(float x) {
  unsigned u = __float_as_uint(x);
  u += 0x7fffu + ((u >> 16) & 1u);   // round-to-nearest-even
  return (unsigned short)(u >> 16);
}
__device__ __forceinline__ float bf2f(unsigned short h) {
  return __uint_as_float(((unsigned)h) << 16);
}
__device__ __forceinline__ void split3_1(float x,
    unsigned short& s0, unsigned short& s1, unsigned short& s2) {
  s0 = f2bf_rne(x); float r1 = x - bf2f(s0);
  s1 = f2bf_rne(r1); float r2 = r1 - bf2f(s1);
  s2 = f2bf_rne(r2);
}

// plane strides (elements) — problem constants
#define QK_PLANE   1605632LL   // Qs/Ks: 128 z * 196 * 64
#define VT_PLANE   1835008LL   // Vts: 128 z * 64 * 224
#define PS_PLANE   5619712LL   // Ps: 128 z * 196 * 224
#define OMG_PLANE  1605632LL   // Omgs: 3136 * 512

// ---------------------------------------------------------------------------
// prep mega-kernel: block ranges do independent jobs.
//  [0,784)      split F    -> Fs    (pstride 1605632)
//  [784,1168)   split Wqkv -> Walls rows 0..1535   (pstride 1048576)
//  [1168,1296)  split W1   -> Walls rows 1536..2047
//  [1296,1360)  Wc = W1 @ Wo (fp32 FMA + fp64 chunks) -> Wcs limbs
//  [1360,1528)  zero Vts pad limbs (kk in [196,224), 3 planes)
//  1528         bcomb[n] = sum_i W1[n,i]*bo[i] + b1[n]
//  1529         biasAll = concat(bqkv, zeros[512])
// ---------------------------------------------------------------------------
__global__ __launch_bounds__(256) void prep_kernel(
    const float* __restrict__ F, unsigned short* __restrict__ Fs,
    const float* __restrict__ Wqkv, const float* __restrict__ W1,
    unsigned short* __restrict__ Walls,
    const float* __restrict__ Wo, unsigned short* __restrict__ Wcs,
    unsigned short* __restrict__ Vts,
    const float* __restrict__ bo, const float* __restrict__ b1,
    float* __restrict__ bcomb,
    const float* __restrict__ bqkv, float* __restrict__ biasAll)
{
  int b = blockIdx.x;
  int tid = threadIdx.x;

  if (b < 1296) {  // ---- splits ----
    const float* X; unsigned short* O; long long i8, pstride;
    if (b < 784)       { X = F;    O = Fs;              pstride = 1605632; i8 = (long long)b * 256 + tid; }
    else if (b < 1168) { X = Wqkv; O = Walls;           pstride = 1048576; i8 = (long long)(b - 784) * 256 + tid; }
    else               { X = W1;   O = Walls + 786432;  pstride = 1048576; i8 = (long long)(b - 1168) * 256 + tid; }
    const float4 aa = *(const float4*)(X + i8 * 8);
    const float4 bb = *(const float4*)(X + i8 * 8 + 4);
    float xs[8] = {aa.x, aa.y, aa.z, aa.w, bb.x, bb.y, bb.z, bb.w};
    bf16x8v o0, o1, o2;
#pragma unroll
    for (int e = 0; e < 8; e++) {
      unsigned short s0, s1, s2;
      split3_1(xs[e], s0, s1, s2);
      o0[e] = (short)s0; o1[e] = (short)s1; o2[e] = (short)s2;
    }
    *(bf16x8v*)(O + i8 * 8)               = o0;
    *(bf16x8v*)(O + pstride + i8 * 8)     = o1;
    *(bf16x8v*)(O + 2 * pstride + i8 * 8) = o2;
    return;
  }

  if (b < 1360) {  // ---- Wc = W1 @ Wo, 64x64 tile, limb output ----
    __shared__ __align__(16) float As[16][68];
    __shared__ __align__(16) float Bs[16][68];
    int local = b - 1296;
    int i0 = (local >> 3) * 64, j0 = (local & 7) * 64;
    int tx = tid & 15, ty = tid >> 4;
    double acc[4][4];
#pragma unroll
    for (int i = 0; i < 4; i++)
#pragma unroll
      for (int j = 0; j < 4; j++) acc[i][j] = 0.0;
    for (int k0 = 0; k0 < 512; k0 += 16) {
#pragma unroll
      for (int rr = 0; rr < 4; rr++) {
        int r = ty + 16 * rr;
        As[tx][r] = W1[(size_t)(i0 + r) * 512 + k0 + tx];
      }
      {
        int j = tid & 63, c0 = (tid >> 6) * 4;
#pragma unroll
        for (int cc = 0; cc < 4; cc++) {
          int c = c0 + cc;
          Bs[c][j] = Wo[(size_t)(k0 + c) * 512 + j0 + j];
        }
      }
      __syncthreads();
      float cf[4][4];
#pragma unroll
      for (int i = 0; i < 4; i++)
#pragma unroll
        for (int j = 0; j < 4; j++) cf[i][j] = 0.0f;
#pragma unroll
      for (int kk = 0; kk < 16; kk++) {
        float4 a4 = *(const float4*)&As[kk][ty * 4];
        float4 b4 = *(const float4*)&Bs[kk][tx * 4];
        float av[4] = {a4.x, a4.y, a4.z, a4.w};
        float bv[4] = {b4.x, b4.y, b4.z, b4.w};
#pragma unroll
        for (int i = 0; i < 4; i++)
#pragma unroll
          for (int j = 0; j < 4; j++) cf[i][j] = fmaf(av[i], bv[j], cf[i][j]);
      }
#pragma unroll
      for (int i = 0; i < 4; i++)
#pragma unroll
        for (int j = 0; j < 4; j++) acc[i][j] += (double)cf[i][j];
      __syncthreads();
    }
#pragma unroll
    for (int i = 0; i < 4; i++) {
      int gi = i0 + ty * 4 + i;
#pragma unroll
      for (int j = 0; j < 4; j++) {
        int gj = j0 + tx * 4 + j;
        float o = (float)acc[i][j];
        unsigned short l0, l1, l2;
        split3_1(o, l0, l1, l2);
        size_t idx = (size_t)gi * 512 + gj;
        Wcs[idx] = l0; Wcs[idx + 262144] = l1; Wcs[idx + 524288] = l2;
      }
    }
    return;
  }

  if (b < 1528) {  // ---- zero Vts pad: 3 planes x 128 z x 64 d x 28 kk ----
    long long p0 = (long long)(b - 1360) * 4096 + tid * 16;
#pragma unroll
    for (int e = 0; e < 16; e++) {
      long long f = p0 + e;                 // [0, 688128)
      int plane = (int)(f / 229376);
      int rem = (int)(f - (long long)plane * 229376);
      int z = rem / 1792;
      int r2 = rem - z * 1792;
      int d = r2 / 28, kk = r2 - d * 28;
      Vts[(size_t)plane * VT_PLANE + (size_t)z * 14336 + (size_t)d * 224 + 196 + kk] = 0;
    }
    return;
  }

  if (b == 1528) {  // ---- bcomb ----
#pragma unroll
    for (int half = 0; half < 2; half++) {
      int n = tid + half * 256;
      const float* wr = W1 + (size_t)n * 512;
      double acc = 0.0;
      for (int k = 0; k < 512; k += 4) {
        float4 wv = *(const float4*)&wr[k];
        float4 bv = *(const float4*)&bo[k];
        acc += (double)wv.x * bv.x + (double)wv.y * bv.y +
               (double)wv.z * bv.z + (double)wv.w * bv.w;
      }
      bcomb[n] = (float)(acc + (double)b1[n]);
    }
    return;
  }

  // b == 1529: biasAll
#pragma unroll
  for (int e = 0; e < 8; e++) {
    int idx = tid * 8 + e;
    biasAll[idx] = (idx < 1536) ? bqkv[idx] : 0.0f;
  }
}

#define GBK 32
#define AROWB 80                 // LDS bytes per row (32 bf16 + 16B pad)
#define SPLIT_SZ (128 * AROWB)   // 10240 B per limb plane
#define BBASE (3 * SPLIT_SZ)     // B tile base: 30720

// ---------------------------------------------------------------------------
// Generalized pre-split bf16x3 MFMA GEMM. As/Bs: 3-plane bf16 limb tensors,
// row strides lda/ldb, plane strides aPlane/bPlane. z-batching via
// zo=z/zInner, zi=z%zInner offsets; split-K via kOff = zi*kOffPerZ.
// bias/res applied on z==0 only. Epilogue modes:
//   0: f32 C[coff + row*ldc + col]
//   1: limb Cl[coff + row*ldc + col] (+clPlane planes)
//   2: qkvw special — col<512: Q limbs; <1024: K limbs; <1536: V limbs
//      transposed [z][d][kk]; else f32 C (FW1) at [row][col-1536].
// ---------------------------------------------------------------------------
__global__ __launch_bounds__(256) void gemm_ps3_kernel(
    const unsigned short* __restrict__ As, const unsigned short* __restrict__ Bs,
    int M, int N, int kLen, int lda, int ldb,
    long long aPlane, long long bPlane,
    int zInner, long long aOuter, long long aInner,
    long long bOuter, long long bInner,
    long long cOuter, long long cInner, int kOffPerZ,
    const float* __restrict__ bias, const float* __restrict__ res, int ldres,
    int mode,
    float* __restrict__ C, int ldc,
    unsigned short* __restrict__ Cl, long long clPlane,
    unsigned short* __restrict__ Qs, unsigned short* __restrict__ Ks,
    unsigned short* __restrict__ Vts)
{
  __shared__ __align__(16) unsigned char smem[2 * BBASE];  // 61440 B

  int z = blockIdx.z;
  int zo = z / zInner, zi = z % zInner;
  As += zo * aOuter + zi * aInner;
  Bs += zo * bOuter + zi * bInner;
  long long coff = zo * cOuter + zi * cInner;
  int kOff = zi * kOffPerZ;

  int tid = threadIdx.x;
  int lane = tid & 63, w = tid >> 6;
  int wrow = w >> 1, wcol = w & 1;
  int i0 = blockIdx.x * 128, j0 = blockIdx.y * 128;

  int r = tid >> 1, hh = tid & 1;
  int arow = i0 + r; if (arow > M - 1) arow = M - 1;
  int brow = j0 + r; if (brow > N - 1) brow = N - 1;
  const unsigned short* ap = As + (size_t)arow * lda + hh * 16 + kOff;
  const unsigned short* bp = Bs + (size_t)brow * ldb + hh * 16 + kOff;
  unsigned swoff = (unsigned)r * AROWB + (unsigned)hh * 32;

  f32x4v acc[4][4];
#pragma unroll
  for (int fi = 0; fi < 4; fi++)
#pragma unroll
    for (int fj = 0; fj < 4; fj++) acc[fi][fj] = (f32x4v){0.f, 0.f, 0.f, 0.f};

  unsigned fr_a = (unsigned)(wrow * 64 + (lane & 15)) * AROWB + (unsigned)(lane >> 4) * 16;
  unsigned fr_b = (unsigned)(wcol * 64 + (lane & 15)) * AROWB + (unsigned)(lane >> 4) * 16 + BBASE;

  for (int k0 = 0; k0 < kLen; k0 += GBK) {
    bf16x8v a0[3], a1[3], b0v[3], b1v[3];
#pragma unroll
    for (int s = 0; s < 3; s++) {
      a0[s]  = *(const bf16x8v*)(ap + s * aPlane + k0);
      a1[s]  = *(const bf16x8v*)(ap + s * aPlane + k0 + 8);
      b0v[s] = *(const bf16x8v*)(bp + s * bPlane + k0);
      b1v[s] = *(const bf16x8v*)(bp + s * bPlane + k0 + 8);
    }
    __syncthreads();  // previous chunk's frag reads complete
#pragma unroll
    for (int s = 0; s < 3; s++) {
      *(bf16x8v*)(smem + s * SPLIT_SZ + swoff)              = a0[s];
      *(bf16x8v*)(smem + s * SPLIT_SZ + swoff + 16)         = a1[s];
      *(bf16x8v*)(smem + BBASE + s * SPLIT_SZ + swoff)      = b0v[s];
      *(bf16x8v*)(smem + BBASE + s * SPLIT_SZ + swoff + 16) = b1v[s];
    }
    __syncthreads();

    bf16x8v af[4][3];
#pragma unroll
    for (int fi = 0; fi < 4; fi++)
#pragma unroll
      for (int s = 0; s < 3; s++)
        af[fi][s] = *(const bf16x8v*)(smem + s * SPLIT_SZ + fr_a + fi * (16 * AROWB));

#pragma unroll
    for (int fj = 0; fj < 4; fj++) {
      bf16x8v b0 = *(const bf16x8v*)(smem + 0 * SPLIT_SZ + fr_b + fj * (16 * AROWB));
      bf16x8v b1 = *(const bf16x8v*)(smem + 1 * SPLIT_SZ + fr_b + fj * (16 * AROWB));
      bf16x8v b2 = *(const bf16x8v*)(smem + 2 * SPLIT_SZ + fr_b + fj * (16 * AROWB));
#pragma unroll
      for (int fi = 0; fi < 4; fi++) {
        f32x4v c = acc[fi][fj];
        c = __builtin_amdgcn_mfma_f32_16x16x32_bf16(af[fi][2], b0, c, 0, 0, 0);
        c = __builtin_amdgcn_mfma_f32_16x16x32_bf16(af[fi][1], b1, c, 0, 0, 0);
        c = __builtin_amdgcn_mfma_f32_16x16x32_bf16(af[fi][0], b2, c, 0, 0, 0);
        c = __builtin_amdgcn_mfma_f32_16x16x32_bf16(af[fi][1], b0, c, 0, 0, 0);
        c = __builtin_amdgcn_mfma_f32_16x16x32_bf16(af[fi][0], b1, c, 0, 0, 0);
        c = __builtin_amdgcn_mfma_f32_16x16x32_bf16(af[fi][0], b0, c, 0, 0, 0);
        acc[fi][fj] = c;
      }
    }
  }

#pragma unroll
  for (int fi = 0; fi < 4; fi++) {
    int row0 = i0 + wrow * 64 + fi * 16 + (lane >> 4) * 4;
#pragma unroll
    for (int fj = 0; fj < 4; fj++) {
      int col = j0 + wcol * 64 + fj * 16 + (lane & 15);
      if (col >= N) continue;
      float badd = (bias && z == 0) ? bias[col] : 0.0f;
      f32x4v v = acc[fi][fj];
#pragma unroll
      for (int rr = 0; rr < 4; rr++) {
        int row = row0 + rr;
        if (row >= M) continue;
        float o = v[rr] + badd;
        if (res && z == 0) o += res[(size_t)row * ldres + col];
        if (mode == 0) {
          C[coff + (size_t)row * ldc + col] = o;
        } else if (mode == 1) {
          unsigned short l0, l1, l2;
          split3_1(o, l0, l1, l2);
          size_t idx = coff + (size_t)row * ldc + col;
          Cl[idx] = l0; Cl[idx + clPlane] = l1; Cl[idx + 2 * clPlane] = l2;
        } else {
          // mode 2 (qkvw): row = token, col in [0,2048)
          int bb = row / 196, q = row - bb * 196;
          if (col < 1024) {
            int cc = col & 511;
            int hd = cc >> 6, d = cc & 63;
            unsigned short* P = (col < 512) ? Qs : Ks;
            size_t idx = ((size_t)(bb * 8 + hd)) * 12544 + (size_t)q * 64 + d;
            unsigned short l0, l1, l2;
            split3_1(o, l0, l1, l2);
            P[idx] = l0; P[idx + QK_PLANE] = l1; P[idx + 2 * QK_PLANE] = l2;
          } else if (col < 1536) {
            int d2 = col - 1024;
            size_t idx = ((size_t)(bb * 8 + (d2 >> 6))) * 14336
                       + (size_t)(d2 & 63) * 224 + q;
            unsigned short l0, l1, l2;
            split3_1(o, l0, l1, l2);
            Vts[idx] = l0; Vts[idx + VT_PLANE] = l1; Vts[idx + 2 * VT_PLANE] = l2;
          } else {
            C[(size_t)row * 512 + (col - 1536)] = o;
          }
        }
      }
    }
  }
}

// ---------------------------------------------------------------------------
// Row softmax (len 196, scale 1/8, fp64 internal) -> P LIMBS, rows padded to
// 224 with zero limbs (kills PV's K-padding exactly: A pad = 0).
// ---------------------------------------------------------------------------
__global__ __launch_bounds__(256) void softmax_kernel(
    const float* __restrict__ S, unsigned short* __restrict__ Ps)
{
  int row = blockIdx.x * 4 + (threadIdx.x >> 6);
  int lane = threadIdx.x & 63;
  const float* sr = S + (size_t)row * 196;
  double v[4];
#pragma unroll
  for (int t = 0; t < 4; t++) {
    int j = lane + 64 * t;
    v[t] = (j < 196) ? (double)sr[j] * 0.125 : -1e300;
  }
  double mx = fmax(fmax(v[0], v[1]), fmax(v[2], v[3]));
#pragma unroll
  for (int off = 1; off < 64; off <<= 1) mx = fmax(mx, __shfl_xor(mx, off));
  double e[4]; double s = 0.0;
#pragma unroll
  for (int t = 0; t < 4; t++) {
    int j = lane + 64 * t;
    e[t] = (j < 196) ? exp(v[t] - mx) : 0.0;
    s += e[t];
  }
#pragma unroll
  for (int off = 1; off < 64; off <<= 1) s += __shfl_xor(s, off);
  double inv = 1.0 / s;
  unsigned short* pr = Ps + (size_t)row * 224;
#pragma unroll
  for (int t = 0; t < 4; t++) {
    int j = lane + 64 * t;
    if (j < 224) {
      float pv = (j < 196) ? (float)(e[t] * inv) : 0.0f;
      unsigned short l0, l1, l2;
      split3_1(pv, l0, l1, l2);
      pr[j] = l0; pr[j + PS_PLANE] = l1; pr[j + 2 * PS_PLANE] = l2;
    }
  }
}

// ---------------------------------------------------------------------------
// Fused LayerNorm (ddof=0, eps=1e-5) + exact GELU + w2 projection.
// h1 arrives as 4 split-K partials (fp64-summed here).
// ---------------------------------------------------------------------------
__global__ __launch_bounds__(256) void lnw2_kernel(
    const float* __restrict__ H, const float* __restrict__ g,
    const float* __restrict__ bb, const float* __restrict__ W2,
    const float* __restrict__ B2, float* __restrict__ Qp)
{
  int row = blockIdx.x;
  const float* hr = H + (size_t)row * 512;
  int tid = threadIdx.x, lane = tid & 63, wv = tid >> 6;
  __shared__ double red[8];
  __shared__ float y[512];
  double x0 = (double)hr[tid]       + (double)hr[tid + 1605632]
            + (double)hr[tid + 3211264] + (double)hr[tid + 4816896];
  double x1 = (double)hr[tid + 256] + (double)hr[tid + 256 + 1605632]
            + (double)hr[tid + 256 + 3211264] + (double)hr[tid + 256 + 4816896];
  double s = x0 + x1;
#pragma unroll
  for (int off = 1; off < 64; off <<= 1) s += __shfl_xor(s, off);
  if (lane == 0) red[wv] = s;
  __syncthreads();
  double mu = (red[0] + red[1] + red[2] + red[3]) * (1.0 / 512.0);
  double d0 = x0 - mu, d1 = x1 - mu;
  double q = d0 * d0 + d1 * d1;
#pragma unroll
  for (int off = 1; off < 64; off <<= 1) q += __shfl_xor(q, off);
  if (lane == 0) red[4 + wv] = q;
  __syncthreads();
  double var = (red[4] + red[5] + red[6] + red[7]) * (1.0 / 512.0);
  double inv = 1.0 / sqrt(var + 1e-5);
  double y0 = d0 * inv * (double)g[tid]       + (double)bb[tid];
  double y1 = d1 * inv * (double)g[tid + 256] + (double)bb[tid + 256];
  const double ISQRT2 = 0.70710678118654752440;
  double z0 = 0.5 * y0 * (1.0 + erf(y0 * ISQRT2));
  double z1 = 0.5 * y1 * (1.0 + erf(y1 * ISQRT2));
  y[tid] = (float)z0;
  y[tid + 256] = (float)z1;
  __syncthreads();

#pragma unroll 1
  for (int t = 0; t < 5; t++) {
    int m = wv * 5 + t;
    const float* wr = W2 + (size_t)m * 512;
    double acc = 0.0;
#pragma unroll
    for (int sE = 0; sE < 8; sE++) {
      int j = lane + 64 * sE;
      acc += (double)y[j] * (double)wr[j];
    }
#pragma unroll
    for (int off = 1; off < 64; off <<= 1) acc += __shfl_xor(acc, off);
    if (lane == 0) Qp[(size_t)row * 20 + m] = (float)(acc + (double)B2[m]);
  }
}

// ---------------------------------------------------------------------------
// Fused topk select + writeout. One block per bn: 640 thr = 10 waves, wave w
// runs the guarded dual-task 32-bit prefix search for m = 2w, 2w+1 (exact
// selection: fp64 product keys, prefix-tie boundary by (low-32 desc, d asc)),
// masks/qif stay in LDS; then all threads stream out[bn] as float4.
// ---------------------------------------------------------------------------
__device__ __forceinline__ void topk_finish32(
    const unsigned* uh, const unsigned* ul, const float* apf,
    unsigned thrh, bool exact, float qp, int m,
    unsigned long long (*mw)[8], float* qf, int lane)
{
  const int KSEL = 51;
  bool sel[8];
  if (exact) {
#pragma unroll
    for (int s = 0; s < 8; s++) sel[s] = (uh[s] >= thrh);
  } else {
    int cg = 0;
#pragma unroll
    for (int s = 0; s < 8; s++) {
      sel[s] = (uh[s] > thrh);
      cg += (int)__popcll(__ballot(sel[s]));
    }
    int need = KSEL - cg;
    bool tk[8];
#pragma unroll
    for (int s = 0; s < 8; s++) tk[s] = false;
    while (need > 0) {
      unsigned long long bk = 0ULL;
#pragma unroll
      for (int s = 0; s < 8; s++) {
        if (uh[s] == thrh && !tk[s]) {
          unsigned long long key = (1ULL << 41)
                                 | ((unsigned long long)ul[s] << 9)
                                 | ((unsigned long long)(7 - s) << 6)
                                 | (unsigned long long)(63 - lane);
          bk = key > bk ? key : bk;
        }
      }
#pragma unroll
      for (int off = 1; off < 64; off <<= 1) {
        unsigned long long ob = __shfl_xor(bk, off);
        bk = ob > bk ? ob : bk;
      }
      if ((int)(63 - (bk & 63ULL)) == lane) {
        int wsI = 7 - (int)((bk >> 6) & 7ULL);
        sel[wsI] = true;
        tk[wsI] = true;
      }
      need--;
    }
  }

  float ss = 0.f;
  unsigned long long selb[8];
#pragma unroll
  for (int s = 0; s < 8; s++) {
    selb[s] = __ballot((int)sel[s]);
    if (sel[s]) ss += apf[s] * apf[s];
  }
#pragma unroll
  for (int off = 1; off < 64; off <<= 1) ss += __shfl_xor(ss, off);
  float nrm = fabsf(qp) * sqrtf(ss);
  float qid = qp / fmaxf(nrm, 1e-6f);
  if (lane == 0) {
    qf[m] = qid;
#pragma unroll
    for (int s = 0; s < 8; s++) mw[m][s] = selb[s];
  }
}

__global__ __launch_bounds__(640) void selwrite_kernel(
    const float* __restrict__ F, const float* __restrict__ T,
    const float* __restrict__ Qp, float* __restrict__ out)
{
  const int KSEL = 51;
  int bn = blockIdx.x;
  int tid = threadIdx.x;
  int lane = tid & 63, w = tid >> 6;   // w in 0..9
  __shared__ unsigned long long mw[20][8];
  __shared__ float qf[20];

  const float* Frow = F + (size_t)bn * 512;

  // ---- select phase: wave w handles m = 2w, 2w+1 ----
  {
    int m0 = 2 * w;
    const float* T0r = T + (size_t)m0 * 512;
    const float* T1r = T0r + 512;
    unsigned uh0[8], ul0[8], uh1[8], ul1[8];
    float ap0[8], ap1[8];
#pragma unroll
    for (int s = 0; s < 8; s++) {
      double fd = (double)Frow[lane + 64 * s];
      double p0 = fd * (double)T0r[lane + 64 * s];   // exact in fp64
      double p1 = fd * (double)T1r[lane + 64 * s];
      unsigned long long u0 =
          (unsigned long long)__double_as_longlong(p0) & 0x7fffffffffffffffULL;
      unsigned long long u1 =
          (unsigned long long)__double_as_longlong(p1) & 0x7fffffffffffffffULL;
      uh0[s] = (unsigned)(u0 >> 32); ul0[s] = (unsigned)u0;
      uh1[s] = (unsigned)(u1 >> 32); ul1[s] = (unsigned)u1;
      ap0[s] = (float)fabs(p0); ap1[s] = (float)fabs(p1);
    }

    unsigned mx0 = 0u, mn0 = 0xffffffffu, mx1 = 0u, mn1 = 0xffffffffu;
#pragma unroll
    for (int s = 0; s < 8; s++) {
      mx0 = uh0[s] > mx0 ? uh0[s] : mx0;  mn0 = uh0[s] < mn0 ? uh0[s] : mn0;
      mx1 = uh1[s] > mx1 ? uh1[s] : mx1;  mn1 = uh1[s] < mn1 ? uh1[s] : mn1;
    }
#pragma unroll
    for (int off = 1; off < 64; off <<= 1) {
      unsigned a = __shfl_xor(mx0, off); mx0 = a > mx0 ? a : mx0;
      unsigned b = __shfl_xor(mn0, off); mn0 = b < mn0 ? b : mn0;
      unsigned c = __shfl_xor(mx1, off); mx1 = c > mx1 ? c : mx1;
      unsigned d = __shfl_xor(mn1, off); mn1 = d < mn1 ? d : mn1;
    }

    unsigned lo0 = mn0, hi0 = mx0 + 1u, lo1 = mn1, hi1 = mx1 + 1u;
    bool ex0 = false, ex1 = false;
    bool dn0 = (hi0 - lo0 <= 1u), dn1 = (hi1 - lo1 <= 1u);
    while (!(dn0 && dn1)) {
      if (!dn0) {   // wave-uniform guard
        unsigned mid = lo0 + ((hi0 - lo0) >> 1);
        int c = 0;
#pragma unroll
        for (int s = 0; s < 8; s++) c += (int)__popcll(__ballot(uh0[s] >= mid));
        if (c >= KSEL) { lo0 = mid; if (c == KSEL) { ex0 = true; dn0 = true; } }
        else hi0 = mid;
        dn0 = dn0 || (hi0 - lo0 <= 1u);
      }
      if (!dn1) {
        unsigned mid = lo1 + ((hi1 - lo1) >> 1);
        int c = 0;
#pragma unroll
        for (int s = 0; s < 8; s++) c += (int)__popcll(__ballot(uh1[s] >= mid));
        if (c >= KSEL) { lo1 = mid; if (c == KSEL) { ex1 = true; dn1 = true; } }
        else hi1 = mid;
        dn1 = dn1 || (hi1 - lo1 <= 1u);
      }
    }
    int g0 = bn * 20 + m0;
    topk_finish32(uh0, ul0, ap0, lo0, ex0, Qp[g0],     m0,     mw, qf, lane);
    topk_finish32(uh1, ul1, ap1, lo1, ex1, Qp[g0 + 1], m0 + 1, mw, qf, lane);
  }
  __syncthreads();

  // ---- write phase: 2560 float4 / 640 threads = 4 each, fully coalesced ----
  float* orow = out + (size_t)bn * 10240;
#pragma unroll
  for (int ph = 0; ph < 4; ph++) {
    int i = ph * 640 + tid;       // float4 index in [0,2560)
    int fe = i * 4;
    float v[4];
#pragma unroll
    for (int e = 0; e < 4; e++) {
      int f = fe + e;
      int dd = f / 20;
      int mm = f - dd * 20;
      bool sel = (mw[mm][dd >> 6] >> (dd & 63)) & 1ULL;
      v[e] = sel ? Frow[dd] * T[(size_t)mm * 512 + dd] * qf[mm] : 0.0f;
    }
    float4 o = {v[0], v[1], v[2], v[3]};
    *(float4*)&orow[fe] = o;
  }
}

extern "C" void kernel_launch(void* const* d_in, const int* in_sizes, int n_in,
                              void* d_out, int out_size, void* d_ws, size_t ws_size,
                              hipStream_t stream) {
  const float* F    = (const float*)d_in[0];   // [3136,512]
  const float* Wqkv = (const float*)d_in[1];   // [1536,512]
  const float* bqkv = (const float*)d_in[2];   // [1536]
  const float* Wo   = (const float*)d_in[3];   // [512,512]
  const float* bo   = (const float*)d_in[4];   // [512]
  const float* W1   = (const float*)d_in[5];   // [512,512]
  const float* b1   = (const float*)d_in[6];   // [512]
  const float* lng  = (const float*)d_in[7];   // [512]
  const float* lnb  = (const float*)d_in[8];   // [512]
  const float* W2   = (const float*)d_in[9];   // [20,512]
  const float* b2   = (const float*)d_in[10];  // [20]
  const float* Tm   = (const float*)d_in[11];  // [20,512]
  float* out = (float*)d_out;

  float* ws = (float*)d_ws;
  // Layout (float offsets). Lifetimes:
  //   Fs/Walls dead after qkvw GEMM; Qs/Ks dead after scores GEMM;
  //   Ps (written by softmax, after those are dead) overlays REGION_A
  //   [Fs|Walls|Qs|Ks] = 8,798,208 fl >= Ps 8,429,568 fl.
  float* scores = ws;                           // 4,917,248
  unsigned short* Vts  = (unsigned short*)(ws + 4917248);   // 2,752,512 fl
  float* FW1    = ws + 7669760;                 // 1,605,632
  unsigned short* Omgs = (unsigned short*)(ws + 9275392);   // 2,408,448 fl
  float* h1p    = ws + 11683840;                // 4 x 1,605,632
  float* Qp     = ws + 18106368;                //    62,720
  float* bcomb  = ws + 18169088;                //       512
  float* biasAll= ws + 18169600;                //     2,048
  unsigned short* Wcs  = (unsigned short*)(ws + 18171648);  //   393,216 fl
  unsigned short* Fs   = (unsigned short*)(ws + 18564864);  // 2,408,448 fl
  unsigned short* Walls= (unsigned short*)(ws + 20973312);  // 1,572,864 fl
  unsigned short* Qs   = (unsigned short*)(ws + 22546176);  // 2,408,448 fl
  unsigned short* Ks   = (unsigned short*)(ws + 24954624);  // 2,408,448 fl
  unsigned short* Ps   = (unsigned short*)(ws + 18564864);  // overlays REGION_A
  dim3 blk(256);

  // 1) prep: splits, Wc=W1@Wo limbs, Vts pad zero, bcomb, biasAll
  prep_kernel<<<dim3(1530), blk, 0, stream>>>(
      F, Fs, Wqkv, W1, Walls, Wo, Wcs, Vts, bo, b1, bcomb, bqkv, biasAll);

  // 2) qkvw = F @ [Wqkv;W1]^T + biasAll   [3136,2048]  (mode 2 epilogue:
  //    Q,K limbs; V limbs transposed -> Vts; FW1 f32)
  gemm_ps3_kernel<<<dim3(25, 16, 1), blk, 0, stream>>>(
      Fs, Walls, 3136, 2048, 512, 512, 512, QK_PLANE, 1048576LL,
      1, 0, 0, 0, 0, 0, 0, 0,
      biasAll, nullptr, 0,
      2, FW1, 512, nullptr, 0, Qs, Ks, Vts);

  // 3) scores[z] = Q[z] @ K[z]^T   [196,196] x 128  (pre-split, mode 0)
  gemm_ps3_kernel<<<dim3(2, 2, 128), blk, 0, stream>>>(
      Qs, Ks, 196, 196, 64, 64, 64, QK_PLANE, QK_PLANE,
      128, 0, 12544, 0, 12544, 0, 38416, 0,
      nullptr, nullptr, 0,
      0, scores, 196, nullptr, 0, nullptr, nullptr, nullptr);

  // 4) softmax rows -> P limbs (padded to 224 with zero limbs)
  softmax_kernel<<<dim3(6272), blk, 0, stream>>>(scores, Ps);

  // 5) Omg[z] = P[z] @ Vt[z]^T  [196,64] x 128 -> Omg limbs (mode 1)
  gemm_ps3_kernel<<<dim3(2, 1, 128), blk, 0, stream>>>(
      Ps, Vts, 196, 64, 224, 224, 224, PS_PLANE, VT_PLANE,
      8, 351232, 43904, 114688, 14336, 100352, 64, 0,
      nullptr, nullptr, 0,
      1, nullptr, 512, Omgs, OMG_PLANE, nullptr, nullptr, nullptr);

  // 6) h1 = Omg @ Wc^T + FW1 + bcomb, split-K x4 -> 4 partials (mode 0)
  gemm_ps3_kernel<<<dim3(25, 4, 4), blk, 0, stream>>>(
      Omgs, Wcs, 3136, 512, 128, 512, 512, OMG_PLANE, 262144LL,
      4, 0, 0, 0, 0, 0, 1605632, 128,
      bcomb, FW1, 512,
      0, h1p, 512, nullptr, 0, nullptr, nullptr, nullptr);

  // 7) fused LayerNorm + exact GELU + w2 -> Qp (sums 4 partials)
  lnw2_kernel<<<dim3(3136), blk, 0, stream>>>(h1p, lng, lnb, W2, b2, Qp);

  // 8) fused selection + writeout (one block per bn, 640 threads)
  selwrite_kernel<<<dim3(3136), dim3(640), 0, stream>>>(F, Tm, Qp, out);
}

// Round 13
// 340.616 us; speedup vs baseline: 1.1705x; 1.1705x over previous
//
#include <hip/hip_runtime.h>
#include <cmath>

// ---------------------------------------------------------------------------
// Problem constants: B=16, N=196, D=512, M=20, H=8, hd=64, k=51
//   tokens = 3136, 3D = 1536
// Algebra: h1 = Omg@(W1*Wo)^T + F@W1^T + (W1*bo + b1)  [Fenh eliminated]
// All GEMMs are pre-split bf16x3 MFMA (no on-the-fly splitting anywhere):
//   qkvw epilogue emits Q,K limbs + V limbs transposed; softmax emits P limbs.
// topk select/write are SEPARATE kernels (R12 fusion regressed: 640-thr
// blocks -> 3 blocks/CU, syncthreads couples max-of-10 searches; separate
// kernels overlap latency-bound and BW-bound work across blocks).
// ---------------------------------------------------------------------------

typedef __attribute__((ext_vector_type(8))) short bf16x8v;
typedef __attribute__((ext_vector_type(4))) float f32x4v;

__device__ __forceinline__ unsigned short f2bf_rne(float x) {
  unsigned u = __float_as_uint(x);
  u += 0x7fffu + ((u >> 16) & 1u);   // round-to-nearest-even
  return (unsigned short)(u >> 16);
}
__device__ __forceinline__ float bf2f(unsigned short h) {
  return __uint_as_float(((unsigned)h) << 16);
}
__device__ __forceinline__ void split3_1(float x,
    unsigned short& s0, unsigned short& s1, unsigned short& s2) {
  s0 = f2bf_rne(x); float r1 = x - bf2f(s0);
  s1 = f2bf_rne(r1); float r2 = r1 - bf2f(s1);
  s2 = f2bf_rne(r2);
}

// plane strides (elements) — problem constants
#define QK_PLANE   1605632LL   // Qs/Ks: 128 z * 196 * 64
#define VT_PLANE   1835008LL   // Vts: 128 z * 64 * 224
#define PS_PLANE   5619712LL   // Ps: 128 z * 196 * 224
#define OMG_PLANE  1605632LL   // Omgs: 3136 * 512

// ---------------------------------------------------------------------------
// prep mega-kernel: block ranges do independent jobs.
//  [0,784)      split F    -> Fs    (pstride 1605632)
//  [784,1168)   split Wqkv -> Walls rows 0..1535   (pstride 1048576)
//  [1168,1296)  split W1   -> Walls rows 1536..2047
//  [1296,1360)  Wc = W1 @ Wo (fp32 FMA + fp64 chunks) -> Wcs limbs
//  [1360,1528)  zero Vts pad limbs (kk in [196,224), 3 planes)
//  1528         bcomb[n] = sum_i W1[n,i]*bo[i] + b1[n]
//  1529         biasAll = concat(bqkv, zeros[512])
// ---------------------------------------------------------------------------
__global__ __launch_bounds__(256) void prep_kernel(
    const float* __restrict__ F, unsigned short* __restrict__ Fs,
    const float* __restrict__ Wqkv, const float* __restrict__ W1,
    unsigned short* __restrict__ Walls,
    const float* __restrict__ Wo, unsigned short* __restrict__ Wcs,
    unsigned short* __restrict__ Vts,
    const float* __restrict__ bo, const float* __restrict__ b1,
    float* __restrict__ bcomb,
    const float* __restrict__ bqkv, float* __restrict__ biasAll)
{
  int b = blockIdx.x;
  int tid = threadIdx.x;

  if (b < 1296) {  // ---- splits ----
    const float* X; unsigned short* O; long long i8, pstride;
    if (b < 784)       { X = F;    O = Fs;              pstride = 1605632; i8 = (long long)b * 256 + tid; }
    else if (b < 1168) { X = Wqkv; O = Walls;           pstride = 1048576; i8 = (long long)(b - 784) * 256 + tid; }
    else               { X = W1;   O = Walls + 786432;  pstride = 1048576; i8 = (long long)(b - 1168) * 256 + tid; }
    const float4 aa = *(const float4*)(X + i8 * 8);
    const float4 bb = *(const float4*)(X + i8 * 8 + 4);
    float xs[8] = {aa.x, aa.y, aa.z, aa.w, bb.x, bb.y, bb.z, bb.w};
    bf16x8v o0, o1, o2;
#pragma unroll
    for (int e = 0; e < 8; e++) {
      unsigned short s0, s1, s2;
      split3_1(xs[e], s0, s1, s2);
      o0[e] = (short)s0; o1[e] = (short)s1; o2[e] = (short)s2;
    }
    *(bf16x8v*)(O + i8 * 8)               = o0;
    *(bf16x8v*)(O + pstride + i8 * 8)     = o1;
    *(bf16x8v*)(O + 2 * pstride + i8 * 8) = o2;
    return;
  }

  if (b < 1360) {  // ---- Wc = W1 @ Wo, 64x64 tile, limb output ----
    __shared__ __align__(16) float As[16][68];
    __shared__ __align__(16) float Bs[16][68];
    int local = b - 1296;
    int i0 = (local >> 3) * 64, j0 = (local & 7) * 64;
    int tx = tid & 15, ty = tid >> 4;
    double acc[4][4];
#pragma unroll
    for (int i = 0; i < 4; i++)
#pragma unroll
      for (int j = 0; j < 4; j++) acc[i][j] = 0.0;
    for (int k0 = 0; k0 < 512; k0 += 16) {
#pragma unroll
      for (int rr = 0; rr < 4; rr++) {
        int r = ty + 16 * rr;
        As[tx][r] = W1[(size_t)(i0 + r) * 512 + k0 + tx];
      }
      {
        int j = tid & 63, c0 = (tid >> 6) * 4;
#pragma unroll
        for (int cc = 0; cc < 4; cc++) {
          int c = c0 + cc;
          Bs[c][j] = Wo[(size_t)(k0 + c) * 512 + j0 + j];
        }
      }
      __syncthreads();
      float cf[4][4];
#pragma unroll
      for (int i = 0; i < 4; i++)
#pragma unroll
        for (int j = 0; j < 4; j++) cf[i][j] = 0.0f;
#pragma unroll
      for (int kk = 0; kk < 16; kk++) {
        float4 a4 = *(const float4*)&As[kk][ty * 4];
        float4 b4 = *(const float4*)&Bs[kk][tx * 4];
        float av[4] = {a4.x, a4.y, a4.z, a4.w};
        float bv[4] = {b4.x, b4.y, b4.z, b4.w};
#pragma unroll
        for (int i = 0; i < 4; i++)
#pragma unroll
          for (int j = 0; j < 4; j++) cf[i][j] = fmaf(av[i], bv[j], cf[i][j]);
      }
#pragma unroll
      for (int i = 0; i < 4; i++)
#pragma unroll
        for (int j = 0; j < 4; j++) acc[i][j] += (double)cf[i][j];
      __syncthreads();
    }
#pragma unroll
    for (int i = 0; i < 4; i++) {
      int gi = i0 + ty * 4 + i;
#pragma unroll
      for (int j = 0; j < 4; j++) {
        int gj = j0 + tx * 4 + j;
        float o = (float)acc[i][j];
        unsigned short l0, l1, l2;
        split3_1(o, l0, l1, l2);
        size_t idx = (size_t)gi * 512 + gj;
        Wcs[idx] = l0; Wcs[idx + 262144] = l1; Wcs[idx + 524288] = l2;
      }
    }
    return;
  }

  if (b < 1528) {  // ---- zero Vts pad: 3 planes x 128 z x 64 d x 28 kk ----
    long long p0 = (long long)(b - 1360) * 4096 + tid * 16;
#pragma unroll
    for (int e = 0; e < 16; e++) {
      long long f = p0 + e;                 // [0, 688128)
      int plane = (int)(f / 229376);
      int rem = (int)(f - (long long)plane * 229376);
      int z = rem / 1792;
      int r2 = rem - z * 1792;
      int d = r2 / 28, kk = r2 - d * 28;
      Vts[(size_t)plane * VT_PLANE + (size_t)z * 14336 + (size_t)d * 224 + 196 + kk] = 0;
    }
    return;
  }

  if (b == 1528) {  // ---- bcomb ----
#pragma unroll
    for (int half = 0; half < 2; half++) {
      int n = tid + half * 256;
      const float* wr = W1 + (size_t)n * 512;
      double acc = 0.0;
      for (int k = 0; k < 512; k += 4) {
        float4 wv = *(const float4*)&wr[k];
        float4 bv = *(const float4*)&bo[k];
        acc += (double)wv.x * bv.x + (double)wv.y * bv.y +
               (double)wv.z * bv.z + (double)wv.w * bv.w;
      }
      bcomb[n] = (float)(acc + (double)b1[n]);
    }
    return;
  }

  // b == 1529: biasAll
#pragma unroll
  for (int e = 0; e < 8; e++) {
    int idx = tid * 8 + e;
    biasAll[idx] = (idx < 1536) ? bqkv[idx] : 0.0f;
  }
}

#define GBK 32
#define AROWB 80                 // LDS bytes per row (32 bf16 + 16B pad)
#define SPLIT_SZ (128 * AROWB)   // 10240 B per limb plane
#define BBASE (3 * SPLIT_SZ)     // B tile base: 30720

// ---------------------------------------------------------------------------
// Generalized pre-split bf16x3 MFMA GEMM. As/Bs: 3-plane bf16 limb tensors,
// row strides lda/ldb, plane strides aPlane/bPlane. z-batching via
// zo=z/zInner, zi=z%zInner offsets; split-K via kOff = zi*kOffPerZ.
// bias/res applied on z==0 only. Epilogue modes:
//   0: f32 C[coff + row*ldc + col]
//   1: limb Cl[coff + row*ldc + col] (+clPlane planes)
//   2: qkvw special — col<512: Q limbs; <1024: K limbs; <1536: V limbs
//      transposed [z][d][kk]; else f32 C (FW1) at [row][col-1536].
// ---------------------------------------------------------------------------
__global__ __launch_bounds__(256) void gemm_ps3_kernel(
    const unsigned short* __restrict__ As, const unsigned short* __restrict__ Bs,
    int M, int N, int kLen, int lda, int ldb,
    long long aPlane, long long bPlane,
    int zInner, long long aOuter, long long aInner,
    long long bOuter, long long bInner,
    long long cOuter, long long cInner, int kOffPerZ,
    const float* __restrict__ bias, const float* __restrict__ res, int ldres,
    int mode,
    float* __restrict__ C, int ldc,
    unsigned short* __restrict__ Cl, long long clPlane,
    unsigned short* __restrict__ Qs, unsigned short* __restrict__ Ks,
    unsigned short* __restrict__ Vts)
{
  __shared__ __align__(16) unsigned char smem[2 * BBASE];  // 61440 B

  int z = blockIdx.z;
  int zo = z / zInner, zi = z % zInner;
  As += zo * aOuter + zi * aInner;
  Bs += zo * bOuter + zi * bInner;
  long long coff = zo * cOuter + zi * cInner;
  int kOff = zi * kOffPerZ;

  int tid = threadIdx.x;
  int lane = tid & 63, w = tid >> 6;
  int wrow = w >> 1, wcol = w & 1;
  int i0 = blockIdx.x * 128, j0 = blockIdx.y * 128;

  int r = tid >> 1, hh = tid & 1;
  int arow = i0 + r; if (arow > M - 1) arow = M - 1;
  int brow = j0 + r; if (brow > N - 1) brow = N - 1;
  const unsigned short* ap = As + (size_t)arow * lda + hh * 16 + kOff;
  const unsigned short* bp = Bs + (size_t)brow * ldb + hh * 16 + kOff;
  unsigned swoff = (unsigned)r * AROWB + (unsigned)hh * 32;

  f32x4v acc[4][4];
#pragma unroll
  for (int fi = 0; fi < 4; fi++)
#pragma unroll
    for (int fj = 0; fj < 4; fj++) acc[fi][fj] = (f32x4v){0.f, 0.f, 0.f, 0.f};

  unsigned fr_a = (unsigned)(wrow * 64 + (lane & 15)) * AROWB + (unsigned)(lane >> 4) * 16;
  unsigned fr_b = (unsigned)(wcol * 64 + (lane & 15)) * AROWB + (unsigned)(lane >> 4) * 16 + BBASE;

  for (int k0 = 0; k0 < kLen; k0 += GBK) {
    bf16x8v a0[3], a1[3], b0v[3], b1v[3];
#pragma unroll
    for (int s = 0; s < 3; s++) {
      a0[s]  = *(const bf16x8v*)(ap + s * aPlane + k0);
      a1[s]  = *(const bf16x8v*)(ap + s * aPlane + k0 + 8);
      b0v[s] = *(const bf16x8v*)(bp + s * bPlane + k0);
      b1v[s] = *(const bf16x8v*)(bp + s * bPlane + k0 + 8);
    }
    __syncthreads();  // previous chunk's frag reads complete
#pragma unroll
    for (int s = 0; s < 3; s++) {
      *(bf16x8v*)(smem + s * SPLIT_SZ + swoff)              = a0[s];
      *(bf16x8v*)(smem + s * SPLIT_SZ + swoff + 16)         = a1[s];
      *(bf16x8v*)(smem + BBASE + s * SPLIT_SZ + swoff)      = b0v[s];
      *(bf16x8v*)(smem + BBASE + s * SPLIT_SZ + swoff + 16) = b1v[s];
    }
    __syncthreads();

    bf16x8v af[4][3];
#pragma unroll
    for (int fi = 0; fi < 4; fi++)
#pragma unroll
      for (int s = 0; s < 3; s++)
        af[fi][s] = *(const bf16x8v*)(smem + s * SPLIT_SZ + fr_a + fi * (16 * AROWB));

#pragma unroll
    for (int fj = 0; fj < 4; fj++) {
      bf16x8v b0 = *(const bf16x8v*)(smem + 0 * SPLIT_SZ + fr_b + fj * (16 * AROWB));
      bf16x8v b1 = *(const bf16x8v*)(smem + 1 * SPLIT_SZ + fr_b + fj * (16 * AROWB));
      bf16x8v b2 = *(const bf16x8v*)(smem + 2 * SPLIT_SZ + fr_b + fj * (16 * AROWB));
#pragma unroll
      for (int fi = 0; fi < 4; fi++) {
        f32x4v c = acc[fi][fj];
        c = __builtin_amdgcn_mfma_f32_16x16x32_bf16(af[fi][2], b0, c, 0, 0, 0);
        c = __builtin_amdgcn_mfma_f32_16x16x32_bf16(af[fi][1], b1, c, 0, 0, 0);
        c = __builtin_amdgcn_mfma_f32_16x16x32_bf16(af[fi][0], b2, c, 0, 0, 0);
        c = __builtin_amdgcn_mfma_f32_16x16x32_bf16(af[fi][1], b0, c, 0, 0, 0);
        c = __builtin_amdgcn_mfma_f32_16x16x32_bf16(af[fi][0], b1, c, 0, 0, 0);
        c = __builtin_amdgcn_mfma_f32_16x16x32_bf16(af[fi][0], b0, c, 0, 0, 0);
        acc[fi][fj] = c;
      }
    }
  }

#pragma unroll
  for (int fi = 0; fi < 4; fi++) {
    int row0 = i0 + wrow * 64 + fi * 16 + (lane >> 4) * 4;
#pragma unroll
    for (int fj = 0; fj < 4; fj++) {
      int col = j0 + wcol * 64 + fj * 16 + (lane & 15);
      if (col >= N) continue;
      float badd = (bias && z == 0) ? bias[col] : 0.0f;
      f32x4v v = acc[fi][fj];
#pragma unroll
      for (int rr = 0; rr < 4; rr++) {
        int row = row0 + rr;
        if (row >= M) continue;
        float o = v[rr] + badd;
        if (res && z == 0) o += res[(size_t)row * ldres + col];
        if (mode == 0) {
          C[coff + (size_t)row * ldc + col] = o;
        } else if (mode == 1) {
          unsigned short l0, l1, l2;
          split3_1(o, l0, l1, l2);
          size_t idx = coff + (size_t)row * ldc + col;
          Cl[idx] = l0; Cl[idx + clPlane] = l1; Cl[idx + 2 * clPlane] = l2;
        } else {
          // mode 2 (qkvw): row = token, col in [0,2048)
          int bb = row / 196, q = row - bb * 196;
          if (col < 1024) {
            int cc = col & 511;
            int hd = cc >> 6, d = cc & 63;
            unsigned short* P = (col < 512) ? Qs : Ks;
            size_t idx = ((size_t)(bb * 8 + hd)) * 12544 + (size_t)q * 64 + d;
            unsigned short l0, l1, l2;
            split3_1(o, l0, l1, l2);
            P[idx] = l0; P[idx + QK_PLANE] = l1; P[idx + 2 * QK_PLANE] = l2;
          } else if (col < 1536) {
            int d2 = col - 1024;
            size_t idx = ((size_t)(bb * 8 + (d2 >> 6))) * 14336
                       + (size_t)(d2 & 63) * 224 + q;
            unsigned short l0, l1, l2;
            split3_1(o, l0, l1, l2);
            Vts[idx] = l0; Vts[idx + VT_PLANE] = l1; Vts[idx + 2 * VT_PLANE] = l2;
          } else {
            C[(size_t)row * 512 + (col - 1536)] = o;
          }
        }
      }
    }
  }
}

// ---------------------------------------------------------------------------
// Row softmax (len 196, scale 1/8, fp64 internal) -> P LIMBS, rows padded to
// 224 with zero limbs (kills PV's K-padding exactly: A pad = 0).
// ---------------------------------------------------------------------------
__global__ __launch_bounds__(256) void softmax_kernel(
    const float* __restrict__ S, unsigned short* __restrict__ Ps)
{
  int row = blockIdx.x * 4 + (threadIdx.x >> 6);
  int lane = threadIdx.x & 63;
  const float* sr = S + (size_t)row * 196;
  double v[4];
#pragma unroll
  for (int t = 0; t < 4; t++) {
    int j = lane + 64 * t;
    v[t] = (j < 196) ? (double)sr[j] * 0.125 : -1e300;
  }
  double mx = fmax(fmax(v[0], v[1]), fmax(v[2], v[3]));
#pragma unroll
  for (int off = 1; off < 64; off <<= 1) mx = fmax(mx, __shfl_xor(mx, off));
  double e[4]; double s = 0.0;
#pragma unroll
  for (int t = 0; t < 4; t++) {
    int j = lane + 64 * t;
    e[t] = (j < 196) ? exp(v[t] - mx) : 0.0;
    s += e[t];
  }
#pragma unroll
  for (int off = 1; off < 64; off <<= 1) s += __shfl_xor(s, off);
  double inv = 1.0 / s;
  unsigned short* pr = Ps + (size_t)row * 224;
#pragma unroll
  for (int t = 0; t < 4; t++) {
    int j = lane + 64 * t;
    if (j < 224) {
      float pv = (j < 196) ? (float)(e[t] * inv) : 0.0f;
      unsigned short l0, l1, l2;
      split3_1(pv, l0, l1, l2);
      pr[j] = l0; pr[j + PS_PLANE] = l1; pr[j + 2 * PS_PLANE] = l2;
    }
  }
}

// ---------------------------------------------------------------------------
// Fused LayerNorm (ddof=0, eps=1e-5) + exact GELU + w2 projection.
// h1 arrives as 4 split-K partials (fp64-summed here).
// ---------------------------------------------------------------------------
__global__ __launch_bounds__(256) void lnw2_kernel(
    const float* __restrict__ H, const float* __restrict__ g,
    const float* __restrict__ bb, const float* __restrict__ W2,
    const float* __restrict__ B2, float* __restrict__ Qp)
{
  int row = blockIdx.x;
  const float* hr = H + (size_t)row * 512;
  int tid = threadIdx.x, lane = tid & 63, wv = tid >> 6;
  __shared__ double red[8];
  __shared__ float y[512];
  double x0 = (double)hr[tid]       + (double)hr[tid + 1605632]
            + (double)hr[tid + 3211264] + (double)hr[tid + 4816896];
  double x1 = (double)hr[tid + 256] + (double)hr[tid + 256 + 1605632]
            + (double)hr[tid + 256 + 3211264] + (double)hr[tid + 256 + 4816896];
  double s = x0 + x1;
#pragma unroll
  for (int off = 1; off < 64; off <<= 1) s += __shfl_xor(s, off);
  if (lane == 0) red[wv] = s;
  __syncthreads();
  double mu = (red[0] + red[1] + red[2] + red[3]) * (1.0 / 512.0);
  double d0 = x0 - mu, d1 = x1 - mu;
  double q = d0 * d0 + d1 * d1;
#pragma unroll
  for (int off = 1; off < 64; off <<= 1) q += __shfl_xor(q, off);
  if (lane == 0) red[4 + wv] = q;
  __syncthreads();
  double var = (red[4] + red[5] + red[6] + red[7]) * (1.0 / 512.0);
  double inv = 1.0 / sqrt(var + 1e-5);
  double y0 = d0 * inv * (double)g[tid]       + (double)bb[tid];
  double y1 = d1 * inv * (double)g[tid + 256] + (double)bb[tid + 256];
  const double ISQRT2 = 0.70710678118654752440;
  double z0 = 0.5 * y0 * (1.0 + erf(y0 * ISQRT2));
  double z1 = 0.5 * y1 * (1.0 + erf(y1 * ISQRT2));
  y[tid] = (float)z0;
  y[tid + 256] = (float)z1;
  __syncthreads();

#pragma unroll 1
  for (int t = 0; t < 5; t++) {
    int m = wv * 5 + t;
    const float* wr = W2 + (size_t)m * 512;
    double acc = 0.0;
#pragma unroll
    for (int sE = 0; sE < 8; sE++) {
      int j = lane + 64 * sE;
      acc += (double)y[j] * (double)wr[j];
    }
#pragma unroll
    for (int off = 1; off < 64; off <<= 1) acc += __shfl_xor(acc, off);
    if (lane == 0) Qp[(size_t)row * 20 + m] = (float)(acc + (double)B2[m]);
  }
}

// ---------------------------------------------------------------------------
// topk selection (R11-proven): 256 thr, two tasks/wave with guarded ballots,
// 32-bit prefix search, min/max seeding, early exit; prefix-tie boundary
// resolved exactly by (low-32 desc, d asc). fp32 finish. Emits 8 ballot
// words (mask) + qif per (bn,m) to global.
// ---------------------------------------------------------------------------
__device__ __forceinline__ void topk_finish32(
    const unsigned* uh, const unsigned* ul, const float* apf,
    unsigned thrh, bool exact, float qp, int g,
    unsigned long long* __restrict__ masks, float* __restrict__ qif, int lane)
{
  const int KSEL = 51;
  bool sel[8];
  if (exact) {
#pragma unroll
    for (int s = 0; s < 8; s++) sel[s] = (uh[s] >= thrh);
  } else {
    int cg = 0;
#pragma unroll
    for (int s = 0; s < 8; s++) {
      sel[s] = (uh[s] > thrh);
      cg += (int)__popcll(__ballot(sel[s]));
    }
    int need = KSEL - cg;
    bool tk[8];
#pragma unroll
    for (int s = 0; s < 8; s++) tk[s] = false;
    while (need > 0) {
      unsigned long long bk = 0ULL;
#pragma unroll
      for (int s = 0; s < 8; s++) {
        if (uh[s] == thrh && !tk[s]) {
          unsigned long long key = (1ULL << 41)
                                 | ((unsigned long long)ul[s] << 9)
                                 | ((unsigned long long)(7 - s) << 6)
                                 | (unsigned long long)(63 - lane);
          bk = key > bk ? key : bk;
        }
      }
#pragma unroll
      for (int off = 1; off < 64; off <<= 1) {
        unsigned long long ob = __shfl_xor(bk, off);
        bk = ob > bk ? ob : bk;
      }
      if ((int)(63 - (bk & 63ULL)) == lane) {
        int wsI = 7 - (int)((bk >> 6) & 7ULL);
        sel[wsI] = true;
        tk[wsI] = true;
      }
      need--;
    }
  }

  float ss = 0.f;
  unsigned long long selb[8];
#pragma unroll
  for (int s = 0; s < 8; s++) {
    selb[s] = __ballot((int)sel[s]);
    if (sel[s]) ss += apf[s] * apf[s];
  }
#pragma unroll
  for (int off = 1; off < 64; off <<= 1) ss += __shfl_xor(ss, off);
  float nrm = fabsf(qp) * sqrtf(ss);
  float qid = qp / fmaxf(nrm, 1e-6f);
  if (lane == 0) {
    qif[g] = qid;
#pragma unroll
    for (int s = 0; s < 8; s++) masks[(size_t)g * 8 + s] = selb[s];
  }
}

__global__ __launch_bounds__(256) void topk_select_kernel(
    const float* __restrict__ F, const float* __restrict__ T,
    const float* __restrict__ Qp, unsigned long long* __restrict__ masks,
    float* __restrict__ qif)
{
  const int KSEL = 51;
  int wid = blockIdx.x * 4 + (threadIdx.x >> 6);
  int lane = threadIdx.x & 63;
  int g0 = wid * 2;                 // two tasks, same bn (20 % 2 == 0)
  int bn = g0 / 20, m0 = g0 - bn * 20;
  const float* Frow = F + (size_t)bn * 512;
  const float* T0r = T + (size_t)m0 * 512;
  const float* T1r = T0r + 512;

  unsigned uh0[8], ul0[8], uh1[8], ul1[8];
  float ap0[8], ap1[8];
#pragma unroll
  for (int s = 0; s < 8; s++) {
    double fd = (double)Frow[lane + 64 * s];
    double p0 = fd * (double)T0r[lane + 64 * s];   // exact in fp64
    double p1 = fd * (double)T1r[lane + 64 * s];
    unsigned long long u0 =
        (unsigned long long)__double_as_longlong(p0) & 0x7fffffffffffffffULL;
    unsigned long long u1 =
        (unsigned long long)__double_as_longlong(p1) & 0x7fffffffffffffffULL;
    uh0[s] = (unsigned)(u0 >> 32); ul0[s] = (unsigned)u0;
    uh1[s] = (unsigned)(u1 >> 32); ul1[s] = (unsigned)u1;
    ap0[s] = (float)fabs(p0); ap1[s] = (float)fabs(p1);
  }

  unsigned mx0 = 0u, mn0 = 0xffffffffu, mx1 = 0u, mn1 = 0xffffffffu;
#pragma unroll
  for (int s = 0; s < 8; s++) {
    mx0 = uh0[s] > mx0 ? uh0[s] : mx0;  mn0 = uh0[s] < mn0 ? uh0[s] : mn0;
    mx1 = uh1[s] > mx1 ? uh1[s] : mx1;  mn1 = uh1[s] < mn1 ? uh1[s] : mn1;
  }
#pragma unroll
  for (int off = 1; off < 64; off <<= 1) {
    unsigned a = __shfl_xor(mx0, off); mx0 = a > mx0 ? a : mx0;
    unsigned b = __shfl_xor(mn0, off); mn0 = b < mn0 ? b : mn0;
    unsigned c = __shfl_xor(mx1, off); mx1 = c > mx1 ? c : mx1;
    unsigned d = __shfl_xor(mn1, off); mn1 = d < mn1 ? d : mn1;
  }

  unsigned lo0 = mn0, hi0 = mx0 + 1u, lo1 = mn1, hi1 = mx1 + 1u;
  bool ex0 = false, ex1 = false;
  bool dn0 = (hi0 - lo0 <= 1u), dn1 = (hi1 - lo1 <= 1u);
  while (!(dn0 && dn1)) {
    if (!dn0) {   // wave-uniform guard
      unsigned mid = lo0 + ((hi0 - lo0) >> 1);
      int c = 0;
#pragma unroll
      for (int s = 0; s < 8; s++) c += (int)__popcll(__ballot(uh0[s] >= mid));
      if (c >= KSEL) { lo0 = mid; if (c == KSEL) { ex0 = true; dn0 = true; } }
      else hi0 = mid;
      dn0 = dn0 || (hi0 - lo0 <= 1u);
    }
    if (!dn1) {
      unsigned mid = lo1 + ((hi1 - lo1) >> 1);
      int c = 0;
#pragma unroll
      for (int s = 0; s < 8; s++) c += (int)__popcll(__ballot(uh1[s] >= mid));
      if (c >= KSEL) { lo1 = mid; if (c == KSEL) { ex1 = true; dn1 = true; } }
      else hi1 = mid;
      dn1 = dn1 || (hi1 - lo1 <= 1u);
    }
  }
  topk_finish32(uh0, ul0, ap0, lo0, ex0, Qp[g0],     g0,     masks, qif, lane);
  topk_finish32(uh1, ul1, ap1, lo1, ex1, Qp[g0 + 1], g0 + 1, masks, qif, lane);
}

// ---------------------------------------------------------------------------
// topk writeout (R11-proven): LDS value tile (two 256-d halves) -> fully
// coalesced contiguous float4 stores, 0 bank conflicts.
// ---------------------------------------------------------------------------
__global__ __launch_bounds__(256) void topk_write_kernel(
    const float* __restrict__ F, const float* __restrict__ T,
    const unsigned long long* __restrict__ masks,
    const float* __restrict__ qif, float* __restrict__ out)
{
  int bn = blockIdx.x;
  int tid = threadIdx.x;
  __shared__ unsigned long long mw[20][8];
  __shared__ float qf[20];
  __shared__ float vt[256][21];   // [d_local][m], stride 21: conflict-free
  if (tid < 160) ((unsigned long long*)mw)[tid] = masks[(size_t)bn * 160 + tid];
  if (tid < 20) qf[tid] = qif[(size_t)bn * 20 + tid];
  const float* Frow = F + (size_t)bn * 512;
  float* orow = out + (size_t)bn * 10240;
  __syncthreads();

#pragma unroll
  for (int half = 0; half < 2; half++) {
    int d = half * 256 + tid;
    float fd = Frow[d];
    int dw = d >> 6, db = d & 63;
#pragma unroll
    for (int m = 0; m < 20; m++) {
      bool sel = (mw[m][dw] >> db) & 1ULL;
      float tv = T[(size_t)m * 512 + d];
      vt[tid][m] = sel ? fd * tv * qf[m] : 0.0f;
    }
    __syncthreads();
#pragma unroll
    for (int k = 0; k < 5; k++) {
      int flat = (k * 256 + tid) * 4;     // element within half [0,5120)
      float v[4];
#pragma unroll
      for (int e = 0; e < 4; e++) {
        int fe = flat + e;
        int dl = fe / 20;
        int mm = fe - dl * 20;
        v[e] = vt[dl][mm];
      }
      float4 o = {v[0], v[1], v[2], v[3]};
      *(float4*)&orow[half * 5120 + flat] = o;
    }
    __syncthreads();
  }
}

extern "C" void kernel_launch(void* const* d_in, const int* in_sizes, int n_in,
                              void* d_out, int out_size, void* d_ws, size_t ws_size,
                              hipStream_t stream) {
  const float* F    = (const float*)d_in[0];   // [3136,512]
  const float* Wqkv = (const float*)d_in[1];   // [1536,512]
  const float* bqkv = (const float*)d_in[2];   // [1536]
  const float* Wo   = (const float*)d_in[3];   // [512,512]
  const float* bo   = (const float*)d_in[4];   // [512]
  const float* W1   = (const float*)d_in[5];   // [512,512]
  const float* b1   = (const float*)d_in[6];   // [512]
  const float* lng  = (const float*)d_in[7];   // [512]
  const float* lnb  = (const float*)d_in[8];   // [512]
  const float* W2   = (const float*)d_in[9];   // [20,512]
  const float* b2   = (const float*)d_in[10];  // [20]
  const float* Tm   = (const float*)d_in[11];  // [20,512]
  float* out = (float*)d_out;

  float* ws = (float*)d_ws;
  // Layout (float offsets). Lifetimes:
  //   Fs/Walls dead after qkvw GEMM; Qs/Ks dead after scores GEMM;
  //   Ps (written by softmax) overlays [Fs|Walls|Qs|Ks] = 8,798,208 fl
  //   >= Ps 8,429,568 fl. masks+qifb overlay scores (dead after softmax).
  float* scores = ws;                           // 4,917,248
  unsigned short* Vts  = (unsigned short*)(ws + 4917248);   // 2,752,512 fl
  float* FW1    = ws + 7669760;                 // 1,605,632
  unsigned short* Omgs = (unsigned short*)(ws + 9275392);   // 2,408,448 fl
  float* h1p    = ws + 11683840;                // 4 x 1,605,632
  float* Qp     = ws + 18106368;                //    62,720
  float* bcomb  = ws + 18169088;                //       512
  float* biasAll= ws + 18169600;                //     2,048
  unsigned short* Wcs  = (unsigned short*)(ws + 18171648);  //   393,216 fl
  unsigned short* Fs   = (unsigned short*)(ws + 18564864);  // 2,408,448 fl
  unsigned short* Walls= (unsigned short*)(ws + 20973312);  // 1,572,864 fl
  unsigned short* Qs   = (unsigned short*)(ws + 22546176);  // 2,408,448 fl
  unsigned short* Ks   = (unsigned short*)(ws + 24954624);  // 2,408,448 fl
  unsigned short* Ps   = (unsigned short*)(ws + 18564864);  // overlays Fs..Ks
  unsigned long long* masks = (unsigned long long*)ws;      // overlays scores
  float* qifb   = ws + 1003520;                 // after masks (1,003,520 fl)
  dim3 blk(256);

  // 1) prep: splits, Wc=W1@Wo limbs, Vts pad zero, bcomb, biasAll
  prep_kernel<<<dim3(1530), blk, 0, stream>>>(
      F, Fs, Wqkv, W1, Walls, Wo, Wcs, Vts, bo, b1, bcomb, bqkv, biasAll);

  // 2) qkvw = F @ [Wqkv;W1]^T + biasAll   [3136,2048]  (mode 2 epilogue:
  //    Q,K limbs; V limbs transposed -> Vts; FW1 f32)
  gemm_ps3_kernel<<<dim3(25, 16, 1), blk, 0, stream>>>(
      Fs, Walls, 3136, 2048, 512, 512, 512, QK_PLANE, 1048576LL,
      1, 0, 0, 0, 0, 0, 0, 0,
      biasAll, nullptr, 0,
      2, FW1, 512, nullptr, 0, Qs, Ks, Vts);

  // 3) scores[z] = Q[z] @ K[z]^T   [196,196] x 128  (pre-split, mode 0)
  gemm_ps3_kernel<<<dim3(2, 2, 128), blk, 0, stream>>>(
      Qs, Ks, 196, 196, 64, 64, 64, QK_PLANE, QK_PLANE,
      128, 0, 12544, 0, 12544, 0, 38416, 0,
      nullptr, nullptr, 0,
      0, scores, 196, nullptr, 0, nullptr, nullptr, nullptr);

  // 4) softmax rows -> P limbs (padded to 224 with zero limbs)
  softmax_kernel<<<dim3(6272), blk, 0, stream>>>(scores, Ps);

  // 5) Omg[z] = P[z] @ Vt[z]^T  [196,64] x 128 -> Omg limbs (mode 1)
  gemm_ps3_kernel<<<dim3(2, 1, 128), blk, 0, stream>>>(
      Ps, Vts, 196, 64, 224, 224, 224, PS_PLANE, VT_PLANE,
      8, 351232, 43904, 114688, 14336, 100352, 64, 0,
      nullptr, nullptr, 0,
      1, nullptr, 512, Omgs, OMG_PLANE, nullptr, nullptr, nullptr);

  // 6) h1 = Omg @ Wc^T + FW1 + bcomb, split-K x4 -> 4 partials (mode 0)
  gemm_ps3_kernel<<<dim3(25, 4, 4), blk, 0, stream>>>(
      Omgs, Wcs, 3136, 512, 128, 512, 512, OMG_PLANE, 262144LL,
      4, 0, 0, 0, 0, 0, 1605632, 128,
      bcomb, FW1, 512,
      0, h1p, 512, nullptr, 0, nullptr, nullptr, nullptr);

  // 7) fused LayerNorm + exact GELU + w2 -> Qp (sums 4 partials)
  lnw2_kernel<<<dim3(3136), blk, 0, stream>>>(h1p, lng, lnb, W2, b2, Qp);

  // 8) selection: 2 tasks/wave, guarded ballots [masks overlay dead scores]
  topk_select_kernel<<<dim3(7840), blk, 0, stream>>>(F, Tm, Qp, masks, qifb);

  // 9) streaming writeout of [B,N,D,M], coalesced via LDS tile
  topk_write_kernel<<<dim3(3136), blk, 0, stream>>>(F, Tm, masks, qifb, out);
}

// Round 14
// 314.173 us; speedup vs baseline: 1.2690x; 1.0842x over previous
//
#include <hip/hip_runtime.h>
#include <cmath>

// ---------------------------------------------------------------------------
// Problem constants: B=16, N=196, D=512, M=20, H=8, hd=64, k=51
//   tokens = 3136, 3D = 1536
// Algebra: h1 = Omg@(W1*Wo)^T + F@W1^T + (W1*bo + b1)  [Fenh eliminated]
// R11 pipeline (proven 316us) + GEMM LDS row-interleaved limbs:
//   208B rows -> 53248B LDS -> 3 blocks/CU (was 61440B -> 2 blocks/CU,
//   occupancy 15%, latency-bound per R13 counters).
// Attention GEMMs stay on-the-fly-split from f32 (R13 showed pre-split
// attention LOSES: P-limb 2B scatters cost RMW traffic > split VALU savings).
// ---------------------------------------------------------------------------

typedef __attribute__((ext_vector_type(8))) short bf16x8v;
typedef __attribute__((ext_vector_type(4))) float f32x4v;

__device__ __forceinline__ unsigned short f2bf_rne(float x) {
  unsigned u = __float_as_uint(x);
  u += 0x7fffu + ((u >> 16) & 1u);   // round-to-nearest-even
  return (unsigned short)(u >> 16);
}
__device__ __forceinline__ float bf2f(unsigned short h) {
  return __uint_as_float(((unsigned)h) << 16);
}
__device__ __forceinline__ void split3_1(float x,
    unsigned short& s0, unsigned short& s1, unsigned short& s2) {
  s0 = f2bf_rne(x); float r1 = x - bf2f(s0);
  s1 = f2bf_rne(r1); float r2 = r1 - bf2f(s1);
  s2 = f2bf_rne(r2);
}

// ---------------------------------------------------------------------------
// prep mega-kernel: block ranges do independent jobs.
//  [0,784)      split F    -> Fs    (pstride 1605632)
//  [784,1168)   split Wqkv -> Walls rows 0..1535   (pstride 1048576)
//  [1168,1296)  split W1   -> Walls rows 1536..2047
//  [1296,1360)  Wc = W1 @ Wo (fp32 FMA + fp64 chunks) -> Wcs limbs
//  [1360,1472)  zero Vt pad (kk in [196,224))
//  1472         bcomb[n] = sum_i W1[n,i]*bo[i] + b1[n]
//  1473         biasAll = concat(bqkv, zeros[512])
// ---------------------------------------------------------------------------
__global__ __launch_bounds__(256) void prep_kernel(
    const float* __restrict__ F, unsigned short* __restrict__ Fs,
    const float* __restrict__ Wqkv, const float* __restrict__ W1,
    unsigned short* __restrict__ Walls,
    const float* __restrict__ Wo, unsigned short* __restrict__ Wcs,
    float* __restrict__ Vt,
    const float* __restrict__ bo, const float* __restrict__ b1,
    float* __restrict__ bcomb,
    const float* __restrict__ bqkv, float* __restrict__ biasAll)
{
  int b = blockIdx.x;
  int tid = threadIdx.x;

  if (b < 1296) {  // ---- splits ----
    const float* X; unsigned short* O; long long i8, pstride;
    if (b < 784)       { X = F;    O = Fs;              pstride = 1605632; i8 = (long long)b * 256 + tid; }
    else if (b < 1168) { X = Wqkv; O = Walls;           pstride = 1048576; i8 = (long long)(b - 784) * 256 + tid; }
    else               { X = W1;   O = Walls + 786432;  pstride = 1048576; i8 = (long long)(b - 1168) * 256 + tid; }
    const float4 aa = *(const float4*)(X + i8 * 8);
    const float4 bb = *(const float4*)(X + i8 * 8 + 4);
    float xs[8] = {aa.x, aa.y, aa.z, aa.w, bb.x, bb.y, bb.z, bb.w};
    bf16x8v o0, o1, o2;
#pragma unroll
    for (int e = 0; e < 8; e++) {
      unsigned short s0, s1, s2;
      split3_1(xs[e], s0, s1, s2);
      o0[e] = (short)s0; o1[e] = (short)s1; o2[e] = (short)s2;
    }
    *(bf16x8v*)(O + i8 * 8)               = o0;
    *(bf16x8v*)(O + pstride + i8 * 8)     = o1;
    *(bf16x8v*)(O + 2 * pstride + i8 * 8) = o2;
    return;
  }

  if (b < 1360) {  // ---- Wc = W1 @ Wo, 64x64 tile, limb output ----
    __shared__ __align__(16) float As[16][68];
    __shared__ __align__(16) float Bs[16][68];
    int local = b - 1296;
    int i0 = (local >> 3) * 64, j0 = (local & 7) * 64;
    int tx = tid & 15, ty = tid >> 4;
    double acc[4][4];
#pragma unroll
    for (int i = 0; i < 4; i++)
#pragma unroll
      for (int j = 0; j < 4; j++) acc[i][j] = 0.0;
    for (int k0 = 0; k0 < 512; k0 += 16) {
#pragma unroll
      for (int rr = 0; rr < 4; rr++) {
        int r = ty + 16 * rr;
        As[tx][r] = W1[(size_t)(i0 + r) * 512 + k0 + tx];
      }
      {
        int j = tid & 63, c0 = (tid >> 6) * 4;
#pragma unroll
        for (int cc = 0; cc < 4; cc++) {
          int c = c0 + cc;
          Bs[c][j] = Wo[(size_t)(k0 + c) * 512 + j0 + j];
        }
      }
      __syncthreads();
      float cf[4][4];
#pragma unroll
      for (int i = 0; i < 4; i++)
#pragma unroll
        for (int j = 0; j < 4; j++) cf[i][j] = 0.0f;
#pragma unroll
      for (int kk = 0; kk < 16; kk++) {
        float4 a4 = *(const float4*)&As[kk][ty * 4];
        float4 b4 = *(const float4*)&Bs[kk][tx * 4];
        float av[4] = {a4.x, a4.y, a4.z, a4.w};
        float bv[4] = {b4.x, b4.y, b4.z, b4.w};
#pragma unroll
        for (int i = 0; i < 4; i++)
#pragma unroll
          for (int j = 0; j < 4; j++) cf[i][j] = fmaf(av[i], bv[j], cf[i][j]);
      }
#pragma unroll
      for (int i = 0; i < 4; i++)
#pragma unroll
        for (int j = 0; j < 4; j++) acc[i][j] += (double)cf[i][j];
      __syncthreads();
    }
#pragma unroll
    for (int i = 0; i < 4; i++) {
      int gi = i0 + ty * 4 + i;
#pragma unroll
      for (int j = 0; j < 4; j++) {
        int gj = j0 + tx * 4 + j;
        float o = (float)acc[i][j];
        unsigned short l0, l1, l2;
        split3_1(o, l0, l1, l2);
        size_t idx = (size_t)gi * 512 + gj;
        Wcs[idx] = l0; Wcs[idx + 262144] = l1; Wcs[idx + 524288] = l2;
      }
    }
    return;
  }

  if (b < 1472) {  // ---- zero Vt pad: 128 z x 64 d x 28 kk = 229376 ----
    long long p0 = (long long)(b - 1360) * 2048 + tid * 8;
#pragma unroll
    for (int e = 0; e < 8; e++) {
      long long pf = p0 + e;
      int z = (int)(pf / 1792);
      int r = (int)(pf - (long long)z * 1792);
      int d = r / 28, kk = r - d * 28;
      Vt[(size_t)z * 14336 + (size_t)d * 224 + 196 + kk] = 0.0f;
    }
    return;
  }

  if (b == 1472) {  // ---- bcomb ----
#pragma unroll
    for (int half = 0; half < 2; half++) {
      int n = tid + half * 256;
      const float* wr = W1 + (size_t)n * 512;
      double acc = 0.0;
      for (int k = 0; k < 512; k += 4) {
        float4 wv = *(const float4*)&wr[k];
        float4 bv = *(const float4*)&bo[k];
        acc += (double)wv.x * bv.x + (double)wv.y * bv.y +
               (double)wv.z * bv.z + (double)wv.w * bv.w;
      }
      bcomb[n] = (float)(acc + (double)b1[n]);
    }
    return;
  }

  // b == 1473: biasAll
#pragma unroll
  for (int e = 0; e < 8; e++) {
    int idx = tid * 8 + e;
    biasAll[idx] = (idx < 1536) ? bqkv[idx] : 0.0f;
  }
}

#define GBK 32
// Row-interleaved limb LDS layout: per row [s0 64B | s1 64B | s2 64B | 16B pad]
#define ROWB 208                 // bytes per row
#define ATILE (128 * ROWB)       // 26624 B per operand tile; total 53248 B
// bank math: addr/4 stride per row = 52 = 20 (mod 32), gcd(20,32)=4 ->
// 16 lanes spread over 8 banks = 2-way (free, m136).

// ---------------------------------------------------------------------------
// Pre-split bf16x3 MFMA GEMM. As/Bs: 3-plane bf16 limb tensors (row stride
// 512, plane strides aPlane/bPlane). N%128==0; M guarded. Split-K via
// blockIdx.z: kOff = z*kLen, C += z*cZStride; bias/res only on z==0.
// Optional VtOut: cols [1024,1536) written transposed into
// Vt[z=(row/196)*8+(d>>6)][d&63][kk=row%196] instead of C.
// ---------------------------------------------------------------------------
__global__ __launch_bounds__(256) void gemm_ps3_kernel(
    const unsigned short* __restrict__ As, const unsigned short* __restrict__ Bs,
    float* __restrict__ C, const float* __restrict__ bias,
    const float* __restrict__ res,
    int M, int N, int ldc, int ldres,
    long long aPlane, long long bPlane,
    int kLen, long long cZStride,
    float* __restrict__ VtOut)
{
  __shared__ __align__(16) unsigned char smem[2 * ATILE];  // 53248 B -> 3 blk/CU

  int z = blockIdx.z;
  int kOff = z * kLen;
  C += (size_t)z * cZStride;

  int tid = threadIdx.x;
  int lane = tid & 63, w = tid >> 6;
  int wrow = w >> 1, wcol = w & 1;
  int i0 = blockIdx.x * 128, j0 = blockIdx.y * 128;

  int r = tid >> 1, hh = tid & 1;
  int arow = i0 + r; if (arow > M - 1) arow = M - 1;
  int brow = j0 + r; if (brow > N - 1) brow = N - 1;
  const unsigned short* ap = As + (size_t)arow * 512 + hh * 16 + kOff;
  const unsigned short* bp = Bs + (size_t)brow * 512 + hh * 16 + kOff;
  unsigned swoff = (unsigned)r * ROWB + (unsigned)hh * 32;

  f32x4v acc[4][4];
#pragma unroll
  for (int fi = 0; fi < 4; fi++)
#pragma unroll
    for (int fj = 0; fj < 4; fj++) acc[fi][fj] = (f32x4v){0.f, 0.f, 0.f, 0.f};

  unsigned fr_a = (unsigned)(wrow * 64 + (lane & 15)) * ROWB + (unsigned)(lane >> 4) * 16;
  unsigned fr_b = (unsigned)(wcol * 64 + (lane & 15)) * ROWB + (unsigned)(lane >> 4) * 16 + ATILE;

  for (int k0 = 0; k0 < kLen; k0 += GBK) {
    bf16x8v a0[3], a1[3], b0v[3], b1v[3];
#pragma unroll
    for (int s = 0; s < 3; s++) {
      a0[s]  = *(const bf16x8v*)(ap + s * aPlane + k0);
      a1[s]  = *(const bf16x8v*)(ap + s * aPlane + k0 + 8);
      b0v[s] = *(const bf16x8v*)(bp + s * bPlane + k0);
      b1v[s] = *(const bf16x8v*)(bp + s * bPlane + k0 + 8);
    }
    __syncthreads();  // previous chunk's frag reads complete
#pragma unroll
    for (int s = 0; s < 3; s++) {
      *(bf16x8v*)(smem + swoff + s * 64)              = a0[s];
      *(bf16x8v*)(smem + swoff + s * 64 + 16)         = a1[s];
      *(bf16x8v*)(smem + ATILE + swoff + s * 64)      = b0v[s];
      *(bf16x8v*)(smem + ATILE + swoff + s * 64 + 16) = b1v[s];
    }
    __syncthreads();

    bf16x8v af[4][3];
#pragma unroll
    for (int fi = 0; fi < 4; fi++)
#pragma unroll
      for (int s = 0; s < 3; s++)
        af[fi][s] = *(const bf16x8v*)(smem + fr_a + fi * (16 * ROWB) + s * 64);

#pragma unroll
    for (int fj = 0; fj < 4; fj++) {
      bf16x8v b0 = *(const bf16x8v*)(smem + fr_b + fj * (16 * ROWB));
      bf16x8v b1 = *(const bf16x8v*)(smem + fr_b + fj * (16 * ROWB) + 64);
      bf16x8v b2 = *(const bf16x8v*)(smem + fr_b + fj * (16 * ROWB) + 128);
#pragma unroll
      for (int fi = 0; fi < 4; fi++) {
        f32x4v c = acc[fi][fj];
        c = __builtin_amdgcn_mfma_f32_16x16x32_bf16(af[fi][2], b0, c, 0, 0, 0);
        c = __builtin_amdgcn_mfma_f32_16x16x32_bf16(af[fi][1], b1, c, 0, 0, 0);
        c = __builtin_amdgcn_mfma_f32_16x16x32_bf16(af[fi][0], b2, c, 0, 0, 0);
        c = __builtin_amdgcn_mfma_f32_16x16x32_bf16(af[fi][1], b0, c, 0, 0, 0);
        c = __builtin_amdgcn_mfma_f32_16x16x32_bf16(af[fi][0], b1, c, 0, 0, 0);
        c = __builtin_amdgcn_mfma_f32_16x16x32_bf16(af[fi][0], b0, c, 0, 0, 0);
        acc[fi][fj] = c;
      }
    }
  }

#pragma unroll
  for (int fi = 0; fi < 4; fi++) {
    int row0 = i0 + wrow * 64 + fi * 16 + (lane >> 4) * 4;
#pragma unroll
    for (int fj = 0; fj < 4; fj++) {
      int col = j0 + wcol * 64 + fj * 16 + (lane & 15);
      if (col >= N) continue;
      float badd = (bias && z == 0) ? bias[col] : 0.0f;
      f32x4v v = acc[fi][fj];
#pragma unroll
      for (int rr = 0; rr < 4; rr++) {
        int row = row0 + rr;
        if (row < M) {
          float o = v[rr] + badd;
          if (res && z == 0) o += res[(size_t)row * ldres + col];
          if (VtOut && col >= 1024 && col < 1536) {
            int d = col - 1024;
            int bb = row / 196;
            int kk = row - bb * 196;
            int zz = bb * 8 + (d >> 6);
            VtOut[(size_t)zz * 14336 + (size_t)(d & 63) * 224 + kk] = o;
          } else {
            C[(size_t)row * ldc + col] = o;
          }
        }
      }
    }
  }
}

// ---------------------------------------------------------------------------
// On-the-fly bf16x3 MFMA GEMM (batched attention GEMMs: strided A/B with
// z-batching, K over-read tolerated). Optional limb output.
// ---------------------------------------------------------------------------
__global__ __launch_bounds__(256) void gemm_bf16x3_kernel(
    const float* __restrict__ A, const float* __restrict__ B,
    float* __restrict__ C, const float* __restrict__ bias,
    const float* __restrict__ res,
    int M, int N, int K, int lda, int ldb, int ldc,
    int zInner, long long aOuter, long long aInner,
    long long bOuter, long long bInner,
    long long cOuter, long long cInner,
    unsigned short* __restrict__ Cl, long long clPlane)
{
  int z = blockIdx.z;
  int zo = z / zInner, zi = z % zInner;
  A += zo * aOuter + zi * aInner;
  B += zo * bOuter + zi * bInner;
  long long coff = zo * cOuter + zi * cInner;
  if (C) C += coff;
  if (Cl) Cl += coff;

  __shared__ __align__(16) unsigned char smem[2 * ATILE];  // 53248 B

  int tid = threadIdx.x;
  int lane = tid & 63, w = tid >> 6;
  int wrow = w >> 1, wcol = w & 1;
  int i0 = blockIdx.x * 128, j0 = blockIdx.y * 128;

  int srow = tid >> 1;
  int skh  = tid & 1;
  int arow = i0 + srow; if (arow > M - 1) arow = M - 1;
  int brow = j0 + srow; if (brow > N - 1) brow = N - 1;
  const float* aptr = A + (size_t)arow * lda + skh * 16;
  const float* bptr = B + (size_t)brow * ldb + skh * 16;
  unsigned swoff = (unsigned)srow * ROWB + (unsigned)skh * 32;

  f32x4v acc[4][4];
#pragma unroll
  for (int fi = 0; fi < 4; fi++)
#pragma unroll
    for (int fj = 0; fj < 4; fj++) acc[fi][fj] = (f32x4v){0.f, 0.f, 0.f, 0.f};

  unsigned fr_a = (unsigned)(wrow * 64 + (lane & 15)) * ROWB + (unsigned)(lane >> 4) * 16;
  unsigned fr_b = (unsigned)(wcol * 64 + (lane & 15)) * ROWB + (unsigned)(lane >> 4) * 16 + ATILE;

  for (int k0 = 0; k0 < K; k0 += GBK) {
    float av[16], bv[16];
    {
      const float4 q0 = *(const float4*)(aptr + k0);
      const float4 q1 = *(const float4*)(aptr + k0 + 4);
      const float4 q2 = *(const float4*)(aptr + k0 + 8);
      const float4 q3 = *(const float4*)(aptr + k0 + 12);
      av[0]=q0.x; av[1]=q0.y; av[2]=q0.z; av[3]=q0.w;
      av[4]=q1.x; av[5]=q1.y; av[6]=q1.z; av[7]=q1.w;
      av[8]=q2.x; av[9]=q2.y; av[10]=q2.z; av[11]=q2.w;
      av[12]=q3.x; av[13]=q3.y; av[14]=q3.z; av[15]=q3.w;
      const float4 r0 = *(const float4*)(bptr + k0);
      const float4 r1 = *(const float4*)(bptr + k0 + 4);
      const float4 r2 = *(const float4*)(bptr + k0 + 8);
      const float4 r3 = *(const float4*)(bptr + k0 + 12);
      bv[0]=r0.x; bv[1]=r0.y; bv[2]=r0.z; bv[3]=r0.w;
      bv[4]=r1.x; bv[5]=r1.y; bv[6]=r1.z; bv[7]=r1.w;
      bv[8]=r2.x; bv[9]=r2.y; bv[10]=r2.z; bv[11]=r2.w;
      bv[12]=r3.x; bv[13]=r3.y; bv[14]=r3.z; bv[15]=r3.w;
    }
    unsigned short ha[3][16], hb[3][16];
#pragma unroll
    for (int e = 0; e < 16; e++) {
      split3_1(av[e], ha[0][e], ha[1][e], ha[2][e]);
      split3_1(bv[e], hb[0][e], hb[1][e], hb[2][e]);
    }
    __syncthreads();
#pragma unroll
    for (int s = 0; s < 3; s++) {
      bf16x8v v0, v1, w0, w1;
#pragma unroll
      for (int e = 0; e < 8; e++) {
        v0[e] = (short)ha[s][e]; v1[e] = (short)ha[s][8 + e];
        w0[e] = (short)hb[s][e]; w1[e] = (short)hb[s][8 + e];
      }
      *(bf16x8v*)(smem + swoff + s * 64)              = v0;
      *(bf16x8v*)(smem + swoff + s * 64 + 16)         = v1;
      *(bf16x8v*)(smem + ATILE + swoff + s * 64)      = w0;
      *(bf16x8v*)(smem + ATILE + swoff + s * 64 + 16) = w1;
    }
    __syncthreads();

    bf16x8v af[4][3];
#pragma unroll
    for (int fi = 0; fi < 4; fi++)
#pragma unroll
      for (int s = 0; s < 3; s++)
        af[fi][s] = *(const bf16x8v*)(smem + fr_a + fi * (16 * ROWB) + s * 64);

#pragma unroll
    for (int fj = 0; fj < 4; fj++) {
      bf16x8v b0 = *(const bf16x8v*)(smem + fr_b + fj * (16 * ROWB));
      bf16x8v b1 = *(const bf16x8v*)(smem + fr_b + fj * (16 * ROWB) + 64);
      bf16x8v b2 = *(const bf16x8v*)(smem + fr_b + fj * (16 * ROWB) + 128);
#pragma unroll
      for (int fi = 0; fi < 4; fi++) {
        f32x4v c = acc[fi][fj];
        c = __builtin_amdgcn_mfma_f32_16x16x32_bf16(af[fi][2], b0, c, 0, 0, 0);
        c = __builtin_amdgcn_mfma_f32_16x16x32_bf16(af[fi][1], b1, c, 0, 0, 0);
        c = __builtin_amdgcn_mfma_f32_16x16x32_bf16(af[fi][0], b2, c, 0, 0, 0);
        c = __builtin_amdgcn_mfma_f32_16x16x32_bf16(af[fi][1], b0, c, 0, 0, 0);
        c = __builtin_amdgcn_mfma_f32_16x16x32_bf16(af[fi][0], b1, c, 0, 0, 0);
        c = __builtin_amdgcn_mfma_f32_16x16x32_bf16(af[fi][0], b0, c, 0, 0, 0);
        acc[fi][fj] = c;
      }
    }
  }

#pragma unroll
  for (int fi = 0; fi < 4; fi++) {
    int row0 = i0 + wrow * 64 + fi * 16 + (lane >> 4) * 4;
#pragma unroll
    for (int fj = 0; fj < 4; fj++) {
      int col = j0 + wcol * 64 + fj * 16 + (lane & 15);
      if (col >= N) continue;
      float badd = bias ? bias[col] : 0.0f;
      f32x4v v = acc[fi][fj];
#pragma unroll
      for (int rr = 0; rr < 4; rr++) {
        int row = row0 + rr;
        if (row < M) {
          float o = v[rr] + badd;
          if (res) o += res[(size_t)row * ldc + col];
          size_t idx = (size_t)row * ldc + col;
          if (Cl) {
            unsigned short l0, l1, l2;
            split3_1(o, l0, l1, l2);
            Cl[idx] = l0; Cl[idx + clPlane] = l1; Cl[idx + 2 * clPlane] = l2;
          } else {
            C[idx] = o;
          }
        }
      }
    }
  }
}

// In-place row softmax of scaled scores: rows of length 196, scale 1/sqrt(64).
__global__ __launch_bounds__(256) void softmax_kernel(float* __restrict__ S)
{
  int row = blockIdx.x * 4 + (threadIdx.x >> 6);
  int lane = threadIdx.x & 63;
  float* sr = S + (size_t)row * 196;
  double v[4];
#pragma unroll
  for (int t = 0; t < 4; t++) {
    int j = lane + 64 * t;
    v[t] = (j < 196) ? (double)sr[j] * 0.125 : -1e300;
  }
  double mx = fmax(fmax(v[0], v[1]), fmax(v[2], v[3]));
#pragma unroll
  for (int off = 1; off < 64; off <<= 1) mx = fmax(mx, __shfl_xor(mx, off));
  double e[4]; double s = 0.0;
#pragma unroll
  for (int t = 0; t < 4; t++) {
    int j = lane + 64 * t;
    e[t] = (j < 196) ? exp(v[t] - mx) : 0.0;
    s += e[t];
  }
#pragma unroll
  for (int off = 1; off < 64; off <<= 1) s += __shfl_xor(s, off);
  double inv = 1.0 / s;
#pragma unroll
  for (int t = 0; t < 4; t++) {
    int j = lane + 64 * t;
    if (j < 196) sr[j] = (float)(e[t] * inv);
  }
}

// ---------------------------------------------------------------------------
// Fused LayerNorm (ddof=0, eps=1e-5) + exact GELU + w2 projection.
// h1 arrives as 4 split-K partials (fp64-summed here).
// ---------------------------------------------------------------------------
__global__ __launch_bounds__(256) void lnw2_kernel(
    const float* __restrict__ H, const float* __restrict__ g,
    const float* __restrict__ bb, const float* __restrict__ W2,
    const float* __restrict__ B2, float* __restrict__ Qp)
{
  int row = blockIdx.x;
  const float* hr = H + (size_t)row * 512;
  int tid = threadIdx.x, lane = tid & 63, wv = tid >> 6;
  __shared__ double red[8];
  __shared__ float y[512];
  double x0 = (double)hr[tid]       + (double)hr[tid + 1605632]
            + (double)hr[tid + 3211264] + (double)hr[tid + 4816896];
  double x1 = (double)hr[tid + 256] + (double)hr[tid + 256 + 1605632]
            + (double)hr[tid + 256 + 3211264] + (double)hr[tid + 256 + 4816896];
  double s = x0 + x1;
#pragma unroll
  for (int off = 1; off < 64; off <<= 1) s += __shfl_xor(s, off);
  if (lane == 0) red[wv] = s;
  __syncthreads();
  double mu = (red[0] + red[1] + red[2] + red[3]) * (1.0 / 512.0);
  double d0 = x0 - mu, d1 = x1 - mu;
  double q = d0 * d0 + d1 * d1;
#pragma unroll
  for (int off = 1; off < 64; off <<= 1) q += __shfl_xor(q, off);
  if (lane == 0) red[4 + wv] = q;
  __syncthreads();
  double var = (red[4] + red[5] + red[6] + red[7]) * (1.0 / 512.0);
  double inv = 1.0 / sqrt(var + 1e-5);
  double y0 = d0 * inv * (double)g[tid]       + (double)bb[tid];
  double y1 = d1 * inv * (double)g[tid + 256] + (double)bb[tid + 256];
  const double ISQRT2 = 0.70710678118654752440;
  double z0 = 0.5 * y0 * (1.0 + erf(y0 * ISQRT2));
  double z1 = 0.5 * y1 * (1.0 + erf(y1 * ISQRT2));
  y[tid] = (float)z0;
  y[tid + 256] = (float)z1;
  __syncthreads();

#pragma unroll 1
  for (int t = 0; t < 5; t++) {
    int m = wv * 5 + t;
    const float* wr = W2 + (size_t)m * 512;
    double acc = 0.0;
#pragma unroll
    for (int sE = 0; sE < 8; sE++) {
      int j = lane + 64 * sE;
      acc += (double)y[j] * (double)wr[j];
    }
#pragma unroll
    for (int off = 1; off < 64; off <<= 1) acc += __shfl_xor(acc, off);
    if (lane == 0) Qp[(size_t)row * 20 + m] = (float)(acc + (double)B2[m]);
  }
}

// ---------------------------------------------------------------------------
// topk selection v5: two tasks/wave, guarded ballots, 32-bit prefix search,
// min/max seeding, early exit; prefix-tie boundary resolved exactly by
// (low-32 desc, d asc). fp32 finish. Emits 8 ballot words + qif per (bn,m).
// ---------------------------------------------------------------------------
__device__ __forceinline__ void topk_finish32(
    const unsigned* uh, const unsigned* ul, const float* apf,
    unsigned thrh, bool exact, float qp, int g,
    unsigned long long* __restrict__ masks, float* __restrict__ qif, int lane)
{
  const int KSEL = 51;
  bool sel[8];
  if (exact) {
#pragma unroll
    for (int s = 0; s < 8; s++) sel[s] = (uh[s] >= thrh);
  } else {
    int cg = 0;
#pragma unroll
    for (int s = 0; s < 8; s++) {
      sel[s] = (uh[s] > thrh);
      cg += (int)__popcll(__ballot(sel[s]));
    }
    int need = KSEL - cg;
    bool tk[8];
#pragma unroll
    for (int s = 0; s < 8; s++) tk[s] = false;
    while (need > 0) {
      unsigned long long bk = 0ULL;
#pragma unroll
      for (int s = 0; s < 8; s++) {
        if (uh[s] == thrh && !tk[s]) {
          unsigned long long key = (1ULL << 41)
                                 | ((unsigned long long)ul[s] << 9)
                                 | ((unsigned long long)(7 - s) << 6)
                                 | (unsigned long long)(63 - lane);
          bk = key > bk ? key : bk;
        }
      }
#pragma unroll
      for (int off = 1; off < 64; off <<= 1) {
        unsigned long long ob = __shfl_xor(bk, off);
        bk = ob > bk ? ob : bk;
      }
      if ((int)(63 - (bk & 63ULL)) == lane) {
        int wsI = 7 - (int)((bk >> 6) & 7ULL);
        sel[wsI] = true;
        tk[wsI] = true;
      }
      need--;
    }
  }

  float ss = 0.f;
  unsigned long long selb[8];
#pragma unroll
  for (int s = 0; s < 8; s++) {
    selb[s] = __ballot((int)sel[s]);
    if (sel[s]) ss += apf[s] * apf[s];
  }
#pragma unroll
  for (int off = 1; off < 64; off <<= 1) ss += __shfl_xor(ss, off);
  float nrm = fabsf(qp) * sqrtf(ss);
  float qid = qp / fmaxf(nrm, 1e-6f);
  if (lane == 0) {
    qif[g] = qid;
#pragma unroll
    for (int s = 0; s < 8; s++) masks[(size_t)g * 8 + s] = selb[s];
  }
}

__global__ __launch_bounds__(256) void topk_select_kernel(
    const float* __restrict__ F, const float* __restrict__ T,
    const float* __restrict__ Qp, unsigned long long* __restrict__ masks,
    float* __restrict__ qif)
{
  const int KSEL = 51;
  int wid = blockIdx.x * 4 + (threadIdx.x >> 6);
  int lane = threadIdx.x & 63;
  int g0 = wid * 2;                 // two tasks, same bn (20 % 2 == 0)
  int bn = g0 / 20, m0 = g0 - bn * 20;
  const float* Frow = F + (size_t)bn * 512;
  const float* T0r = T + (size_t)m0 * 512;
  const float* T1r = T0r + 512;

  unsigned uh0[8], ul0[8], uh1[8], ul1[8];
  float ap0[8], ap1[8];
#pragma unroll
  for (int s = 0; s < 8; s++) {
    double fd = (double)Frow[lane + 64 * s];
    double p0 = fd * (double)T0r[lane + 64 * s];   // exact in fp64
    double p1 = fd * (double)T1r[lane + 64 * s];
    unsigned long long u0 =
        (unsigned long long)__double_as_longlong(p0) & 0x7fffffffffffffffULL;
    unsigned long long u1 =
        (unsigned long long)__double_as_longlong(p1) & 0x7fffffffffffffffULL;
    uh0[s] = (unsigned)(u0 >> 32); ul0[s] = (unsigned)u0;
    uh1[s] = (unsigned)(u1 >> 32); ul1[s] = (unsigned)u1;
    ap0[s] = (float)fabs(p0); ap1[s] = (float)fabs(p1);
  }

  unsigned mx0 = 0u, mn0 = 0xffffffffu, mx1 = 0u, mn1 = 0xffffffffu;
#pragma unroll
  for (int s = 0; s < 8; s++) {
    mx0 = uh0[s] > mx0 ? uh0[s] : mx0;  mn0 = uh0[s] < mn0 ? uh0[s] : mn0;
    mx1 = uh1[s] > mx1 ? uh1[s] : mx1;  mn1 = uh1[s] < mn1 ? uh1[s] : mn1;
  }
#pragma unroll
  for (int off = 1; off < 64; off <<= 1) {
    unsigned a = __shfl_xor(mx0, off); mx0 = a > mx0 ? a : mx0;
    unsigned b = __shfl_xor(mn0, off); mn0 = b < mn0 ? b : mn0;
    unsigned c = __shfl_xor(mx1, off); mx1 = c > mx1 ? c : mx1;
    unsigned d = __shfl_xor(mn1, off); mn1 = d < mn1 ? d : mn1;
  }

  unsigned lo0 = mn0, hi0 = mx0 + 1u, lo1 = mn1, hi1 = mx1 + 1u;
  bool ex0 = false, ex1 = false;
  bool dn0 = (hi0 - lo0 <= 1u), dn1 = (hi1 - lo1 <= 1u);
  while (!(dn0 && dn1)) {
    if (!dn0) {   // wave-uniform guard
      unsigned mid = lo0 + ((hi0 - lo0) >> 1);
      int c = 0;
#pragma unroll
      for (int s = 0; s < 8; s++) c += (int)__popcll(__ballot(uh0[s] >= mid));
      if (c >= KSEL) { lo0 = mid; if (c == KSEL) { ex0 = true; dn0 = true; } }
      else hi0 = mid;
      dn0 = dn0 || (hi0 - lo0 <= 1u);
    }
    if (!dn1) {
      unsigned mid = lo1 + ((hi1 - lo1) >> 1);
      int c = 0;
#pragma unroll
      for (int s = 0; s < 8; s++) c += (int)__popcll(__ballot(uh1[s] >= mid));
      if (c >= KSEL) { lo1 = mid; if (c == KSEL) { ex1 = true; dn1 = true; } }
      else hi1 = mid;
      dn1 = dn1 || (hi1 - lo1 <= 1u);
    }
  }
  topk_finish32(uh0, ul0, ap0, lo0, ex0, Qp[g0],     g0,     masks, qif, lane);
  topk_finish32(uh1, ul1, ap1, lo1, ex1, Qp[g0 + 1], g0 + 1, masks, qif, lane);
}

// ---------------------------------------------------------------------------
// topk writeout: LDS value tile (two 256-d halves) -> fully coalesced
// contiguous float4 stores, 0 bank conflicts.
// ---------------------------------------------------------------------------
__global__ __launch_bounds__(256) void topk_write_kernel(
    const float* __restrict__ F, const float* __restrict__ T,
    const unsigned long long* __restrict__ masks,
    const float* __restrict__ qif, float* __restrict__ out)
{
  int bn = blockIdx.x;
  int tid = threadIdx.x;
  __shared__ unsigned long long mw[20][8];
  __shared__ float qf[20];
  __shared__ float vt[256][21];   // [d_local][m], stride 21: conflict-free
  if (tid < 160) ((unsigned long long*)mw)[tid] = masks[(size_t)bn * 160 + tid];
  if (tid < 20) qf[tid] = qif[(size_t)bn * 20 + tid];
  const float* Frow = F + (size_t)bn * 512;
  float* orow = out + (size_t)bn * 10240;
  __syncthreads();

#pragma unroll
  for (int half = 0; half < 2; half++) {
    int d = half * 256 + tid;
    float fd = Frow[d];
    int dw = d >> 6, db = d & 63;
#pragma unroll
    for (int m = 0; m < 20; m++) {
      bool sel = (mw[m][dw] >> db) & 1ULL;
      float tv = T[(size_t)m * 512 + d];
      vt[tid][m] = sel ? fd * tv * qf[m] : 0.0f;
    }
    __syncthreads();
#pragma unroll
    for (int k = 0; k < 5; k++) {
      int flat = (k * 256 + tid) * 4;     // element within half [0,5120)
      float v[4];
#pragma unroll
      for (int e = 0; e < 4; e++) {
        int fe = flat + e;
        int dl = fe / 20;
        int mm = fe - dl * 20;
        v[e] = vt[dl][mm];
      }
      float4 o = {v[0], v[1], v[2], v[3]};
      *(float4*)&orow[half * 5120 + flat] = o;
    }
    __syncthreads();
  }
}

extern "C" void kernel_launch(void* const* d_in, const int* in_sizes, int n_in,
                              void* d_out, int out_size, void* d_ws, size_t ws_size,
                              hipStream_t stream) {
  const float* F    = (const float*)d_in[0];   // [3136,512]
  const float* Wqkv = (const float*)d_in[1];   // [1536,512]
  const float* bqkv = (const float*)d_in[2];   // [1536]
  const float* Wo   = (const float*)d_in[3];   // [512,512]
  const float* bo   = (const float*)d_in[4];   // [512]
  const float* W1   = (const float*)d_in[5];   // [512,512]
  const float* b1   = (const float*)d_in[6];   // [512]
  const float* lng  = (const float*)d_in[7];   // [512]
  const float* lnb  = (const float*)d_in[8];   // [512]
  const float* W2   = (const float*)d_in[9];   // [20,512]
  const float* b2   = (const float*)d_in[10];  // [20]
  const float* Tm   = (const float*)d_in[11];  // [20,512]
  float* out = (float*)d_out;

  float* ws = (float*)d_ws;
  // Dedicated regions (R11-proven layout, ~110 MB total):
  float* qkvw   = ws;                          // [3136,2048] = 6,422,528
  float* scores = ws + 6422528;                // 4,917,248
  float* Vt     = ws + 11339776;               // 128*64*224 = 1,835,008
  float* h1p    = ws + 13174784;               // 4 x 1,605,632 = 6,422,528
  float* Qp     = ws + 19597312;               //    62,720
  float* bcomb  = ws + 19660032;               //       512
  float* biasAll= ws + 19660544;               //     2,048
  unsigned long long* masks = (unsigned long long*)(ws + 19662592);  // 1,003,520 fl
  float* qifb   = ws + 20666112;               //    62,720
  unsigned short* Fs    = (unsigned short*)(ws + 20728832);  // 2,408,448 fl
  unsigned short* Walls = (unsigned short*)(ws + 23137280);  // 1,572,864 fl
  unsigned short* Wcs   = (unsigned short*)(ws + 24710144);  //   393,216 fl
  unsigned short* Omgs  = (unsigned short*)(ws + 25103360);  // 2,408,448 fl
  dim3 blk(256);

  // 1) prep: limb splits (F, Wqkv+W1 -> Walls), Wc = W1@Wo -> limbs,
  //    Vt pad zero, bcomb, biasAll
  prep_kernel<<<dim3(1474), blk, 0, stream>>>(
      F, Fs, Wqkv, W1, Walls, Wo, Wcs, Vt, bo, b1, bcomb, bqkv, biasAll);

  // 2) qkvw = F @ [Wqkv;W1]^T + biasAll      [3136,2048]  (pre-split MFMA)
  //    cols [0,1024): Q,K -> qkvw; [1024,1536): V -> Vt transposed;
  //    [1536,2048): F@W1^T -> qkvw (res for h1)
  gemm_ps3_kernel<<<dim3(25, 16, 1), blk, 0, stream>>>(
      Fs, Walls, qkvw, biasAll, nullptr,
      3136, 2048, 2048, 0, 1605632LL, 1048576LL, 512, 0LL, Vt);

  // 3) scores[b,h] = Q[b,h] @ K[b,h]^T       [196,196] x 128  (on-the-fly)
  gemm_bf16x3_kernel<<<dim3(2, 2, 128), blk, 0, stream>>>(
      qkvw, qkvw + 512, scores, nullptr, nullptr,
      196, 196, 64, 2048, 2048, 196,
      8, 196LL * 2048, 64, 196LL * 2048, 64, 8LL * 38416, 38416,
      nullptr, 0);

  // 4) softmax rows (scale 0.125 inside)
  softmax_kernel<<<dim3(6272), blk, 0, stream>>>(scores);

  // 5) O[b,h] = P[b,h] @ Vt[b,h]^T -> Omg LIMBS directly
  gemm_bf16x3_kernel<<<dim3(2, 1, 128), blk, 0, stream>>>(
      scores, Vt, nullptr, nullptr, nullptr,
      196, 64, 196, 196, 224, 512,
      8, 8LL * 38416, 38416, 8LL * 14336, 14336, 100352, 64,
      Omgs, 1605632LL);

  // 6) h1 = Omg @ Wc^T + FW1 + bcomb, split-K x4 -> 4 partials
  gemm_ps3_kernel<<<dim3(25, 4, 4), blk, 0, stream>>>(
      Omgs, Wcs, h1p, bcomb, qkvw + 1536,
      3136, 512, 512, 2048, 1605632LL, 262144LL, 128, 1605632LL, nullptr);

  // 7) fused LayerNorm + exact GELU + w2 -> Qp  (sums 4 partials)
  lnw2_kernel<<<dim3(3136), blk, 0, stream>>>(h1p, lng, lnb, W2, b2, Qp);

  // 8) selection: 2 tasks/wave, guarded ballots
  topk_select_kernel<<<dim3(7840), blk, 0, stream>>>(F, Tm, Qp, masks, qifb);

  // 9) streaming writeout of [B,N,D,M], coalesced via LDS tile
  topk_write_kernel<<<dim3(3136), blk, 0, stream>>>(F, Tm, masks, qifb, out);
}